// Round 1
// baseline (1232.909 us; speedup 1.0000x reference)
//
#include <hip/hip_runtime.h>
#include <math.h>

// Problem constants
constexpr int Bn = 4;
constexpr int Tn = 2048;
constexpr int Dn = 512;
constexpr int Hn = 8;
constexpr int HDn = 64;       // head dim
constexpr int Fn = 2048;
constexpr int WIN = 128;
constexpr float EPS = 1e-5f;
constexpr int Mrows = Bn * Tn;          // 8192
constexpr int QKVD = 3 * Dn;            // 1536

// ---------------- LayerNorm: one wave (64 lanes) per row of 512 ----------------
__global__ __launch_bounds__(64) void ln_kernel(const float* __restrict__ x,
                                                const float* __restrict__ g,
                                                const float* __restrict__ b,
                                                float* __restrict__ y)
{
    int row = blockIdx.x;
    int lane = threadIdx.x;
    const float4* xr = (const float4*)(x + (size_t)row * Dn);
    float4 v0 = xr[lane];
    float4 v1 = xr[lane + 64];
    float s = v0.x + v0.y + v0.z + v0.w + v1.x + v1.y + v1.z + v1.w;
#pragma unroll
    for (int off = 32; off >= 1; off >>= 1) s += __shfl_xor(s, off, 64);
    float mu = s * (1.0f / Dn);
    float d0x = v0.x - mu, d0y = v0.y - mu, d0z = v0.z - mu, d0w = v0.w - mu;
    float d1x = v1.x - mu, d1y = v1.y - mu, d1z = v1.z - mu, d1w = v1.w - mu;
    float q = d0x*d0x + d0y*d0y + d0z*d0z + d0w*d0w
            + d1x*d1x + d1y*d1y + d1z*d1z + d1w*d1w;
#pragma unroll
    for (int off = 32; off >= 1; off >>= 1) q += __shfl_xor(q, off, 64);
    float inv = rsqrtf(q * (1.0f / Dn) + EPS);
    const float4* gr = (const float4*)g;
    const float4* br = (const float4*)b;
    float4 g0 = gr[lane], g1 = gr[lane + 64];
    float4 b0 = br[lane], b1 = br[lane + 64];
    float4 o0, o1;
    o0.x = d0x * inv * g0.x + b0.x;
    o0.y = d0y * inv * g0.y + b0.y;
    o0.z = d0z * inv * g0.z + b0.z;
    o0.w = d0w * inv * g0.w + b0.w;
    o1.x = d1x * inv * g1.x + b1.x;
    o1.y = d1y * inv * g1.y + b1.y;
    o1.z = d1z * inv * g1.z + b1.z;
    o1.w = d1w * inv * g1.w + b1.w;
    float4* yr = (float4*)(y + (size_t)row * Dn);
    yr[lane] = o0;
    yr[lane + 64] = o1;
}

// ---------------- GEMM (NT): C[m,n] = sum_k A[m,k] * Bw[n,k] + bias[n] (+epilogue)
// MODE 0: bias only. MODE 1: bias + resid[m,n]. MODE 2: bias + exact GELU.
__device__ __forceinline__ float gelu_exact(float v) {
    return 0.5f * v * (1.0f + erff(v * 0.70710678118654752f));
}

template <int MODE>
__global__ __launch_bounds__(256) void gemm_nt(const float* __restrict__ A,
                                               const float* __restrict__ Bw,
                                               const float* __restrict__ bias,
                                               const float* __restrict__ resid,
                                               float* __restrict__ C,
                                               int M, int N, int K)
{
    __shared__ float As[16][68];
    __shared__ float Bs[16][68];
    int tid = threadIdx.x;
    int tx = tid & 15, ty = tid >> 4;
    int m0 = blockIdx.y * 64, n0 = blockIdx.x * 64;
    float c[4][4] = {};

    int arow = tid >> 2;            // 0..63
    int acol = (tid & 3) * 4;       // 0,4,8,12
    const float* Aptr = A + (size_t)(m0 + arow) * K + acol;
    const float* Bptr = Bw + (size_t)(n0 + arow) * K + acol;

    for (int kt = 0; kt < K; kt += 16) {
        float4 av = *(const float4*)(Aptr + kt);
        float4 bv = *(const float4*)(Bptr + kt);
        __syncthreads();   // protect previous iteration's reads before overwrite
        As[acol + 0][arow] = av.x; As[acol + 1][arow] = av.y;
        As[acol + 2][arow] = av.z; As[acol + 3][arow] = av.w;
        Bs[acol + 0][arow] = bv.x; Bs[acol + 1][arow] = bv.y;
        Bs[acol + 2][arow] = bv.z; Bs[acol + 3][arow] = bv.w;
        __syncthreads();
#pragma unroll
        for (int kk = 0; kk < 16; ++kk) {
            float a0 = As[kk][ty * 4 + 0];
            float a1 = As[kk][ty * 4 + 1];
            float a2 = As[kk][ty * 4 + 2];
            float a3 = As[kk][ty * 4 + 3];
            float b0 = Bs[kk][tx * 4 + 0];
            float b1 = Bs[kk][tx * 4 + 1];
            float b2 = Bs[kk][tx * 4 + 2];
            float b3 = Bs[kk][tx * 4 + 3];
            c[0][0] += a0 * b0; c[0][1] += a0 * b1; c[0][2] += a0 * b2; c[0][3] += a0 * b3;
            c[1][0] += a1 * b0; c[1][1] += a1 * b1; c[1][2] += a1 * b2; c[1][3] += a1 * b3;
            c[2][0] += a2 * b0; c[2][1] += a2 * b1; c[2][2] += a2 * b2; c[2][3] += a2 * b3;
            c[3][0] += a3 * b0; c[3][1] += a3 * b1; c[3][2] += a3 * b2; c[3][3] += a3 * b3;
        }
    }

    int nb = n0 + tx * 4;
    float4 bv = *(const float4*)(bias + nb);
#pragma unroll
    for (int i = 0; i < 4; ++i) {
        size_t idx = (size_t)(m0 + ty * 4 + i) * N + nb;
        float4 r;
        r.x = c[i][0] + bv.x;
        r.y = c[i][1] + bv.y;
        r.z = c[i][2] + bv.z;
        r.w = c[i][3] + bv.w;
        if (MODE == 1) {
            float4 rv = *(const float4*)(resid + idx);
            r.x += rv.x; r.y += rv.y; r.z += rv.z; r.w += rv.w;
        }
        if (MODE == 2) {
            r.x = gelu_exact(r.x); r.y = gelu_exact(r.y);
            r.z = gelu_exact(r.z); r.w = gelu_exact(r.w);
        }
        *(float4*)(C + idx) = r;
    }
}

// ---------------- Sliding-window attention: one wave per (b,h,t) query ----------------
// qkv layout: (B,T,1536) with q=[0:512), k=[512:1024), v=[1024:1536); head h at h*64.
// ctx layout: (B,T,512) with head h at h*64.
__global__ __launch_bounds__(256) void attn_kernel(const float* __restrict__ qkv,
                                                   float* __restrict__ ctx)
{
    __shared__ float qs[4][64];
    __shared__ float pb[4][128];
    int wid = threadIdx.x >> 6;
    int lane = threadIdx.x & 63;
    int g = blockIdx.x * 4 + wid;          // ((b*H + h)*T + t)
    int t = g & (Tn - 1);
    int bh = g >> 11;                       // /2048
    int h = bh & (Hn - 1);
    int b = bh >> 3;

    const float* qrow = qkv + ((size_t)(b * Tn + t)) * QKVD + h * HDn;
    qs[wid][lane] = qrow[lane];
    __syncthreads();

    int lo = t - (WIN - 1); if (lo < 0) lo = 0;
    int L = t - lo + 1;                     // 1..128
    int j0 = lo + lane, j1 = lo + 64 + lane;
    bool ok0 = (j0 <= t), ok1 = (j1 <= t);
    float s0 = -INFINITY, s1 = -INFINITY;
    if (ok0) {
        const float4* kp = (const float4*)(qkv + ((size_t)(b * Tn + j0)) * QKVD + Dn + h * HDn);
        float acc = 0.f;
#pragma unroll
        for (int d4 = 0; d4 < 16; ++d4) {
            float4 kv = kp[d4];
            acc += qs[wid][4 * d4 + 0] * kv.x + qs[wid][4 * d4 + 1] * kv.y
                 + qs[wid][4 * d4 + 2] * kv.z + qs[wid][4 * d4 + 3] * kv.w;
        }
        s0 = acc * 0.125f;                  // 1/sqrt(64)
    }
    if (ok1) {
        const float4* kp = (const float4*)(qkv + ((size_t)(b * Tn + j1)) * QKVD + Dn + h * HDn);
        float acc = 0.f;
#pragma unroll
        for (int d4 = 0; d4 < 16; ++d4) {
            float4 kv = kp[d4];
            acc += qs[wid][4 * d4 + 0] * kv.x + qs[wid][4 * d4 + 1] * kv.y
                 + qs[wid][4 * d4 + 2] * kv.z + qs[wid][4 * d4 + 3] * kv.w;
        }
        s1 = acc * 0.125f;
    }
    float m = fmaxf(s0, s1);
#pragma unroll
    for (int off = 32; off >= 1; off >>= 1) m = fmaxf(m, __shfl_xor(m, off, 64));
    float p0 = ok0 ? expf(s0 - m) : 0.f;
    float p1 = ok1 ? expf(s1 - m) : 0.f;
    float den = p0 + p1;
#pragma unroll
    for (int off = 32; off >= 1; off >>= 1) den += __shfl_xor(den, off, 64);
    float inv = 1.0f / den;
    pb[wid][lane] = p0;
    pb[wid][64 + lane] = p1;
    __syncthreads();

    float acc = 0.f;
    const float* vp = qkv + ((size_t)(b * Tn + lo)) * QKVD + 2 * Dn + h * HDn + lane;
    for (int j = 0; j < L; ++j) acc += pb[wid][j] * vp[(size_t)j * QKVD];
    ctx[((size_t)(b * Tn + t)) * Dn + h * HDn + lane] = acc * inv;
}

extern "C" void kernel_launch(void* const* d_in, const int* in_sizes, int n_in,
                              void* d_out, int out_size, void* d_ws, size_t ws_size,
                              hipStream_t stream)
{
    const float* x         = (const float*)d_in[0];
    const float* in_proj_w = (const float*)d_in[1];
    const float* in_proj_b = (const float*)d_in[2];
    const float* out_w     = (const float*)d_in[3];
    const float* out_b     = (const float*)d_in[4];
    const float* ln1_g     = (const float*)d_in[5];
    const float* ln1_b     = (const float*)d_in[6];
    const float* ln2_g     = (const float*)d_in[7];
    const float* ln2_b     = (const float*)d_in[8];
    const float* w1        = (const float*)d_in[9];
    const float* b1        = (const float*)d_in[10];
    const float* w2        = (const float*)d_in[11];
    const float* b2        = (const float*)d_in[12];
    float* out = (float*)d_out;

    // Workspace layout (80 MB):
    //   region A @ 0        : 64 MB  — qkv (B,T,1536) then h (B,T,2048)
    //   region B @ 64 MB    : 16 MB  — x2 -> ctx -> x3   (each dead before reuse)
    char* ws = (char*)d_ws;
    float* regA = (float*)ws;
    float* regB = (float*)(ws + (size_t)64 * 1024 * 1024);

    // 1) x2 = LN1(x)
    ln_kernel<<<Mrows, 64, 0, stream>>>(x, ln1_g, ln1_b, regB);
    // 2) qkv = x2 @ in_proj_w^T + in_proj_b
    gemm_nt<0><<<dim3(QKVD / 64, Mrows / 64), 256, 0, stream>>>(
        regB, in_proj_w, in_proj_b, nullptr, regA, Mrows, QKVD, Dn);
    // 3) ctx = sliding-window attention(qkv)
    attn_kernel<<<(Bn * Hn * Tn) / 4, 256, 0, stream>>>(regA, regB);
    // 4) xres = x + ctx @ out_w^T + out_b   (into d_out)
    gemm_nt<1><<<dim3(Dn / 64, Mrows / 64), 256, 0, stream>>>(
        regB, out_w, out_b, x, out, Mrows, Dn, Dn);
    // 5) x3 = LN2(xres)
    ln_kernel<<<Mrows, 64, 0, stream>>>(out, ln2_g, ln2_b, regB);
    // 6) h = gelu(x3 @ w1^T + b1)
    gemm_nt<2><<<dim3(Fn / 64, Mrows / 64), 256, 0, stream>>>(
        regB, w1, b1, nullptr, regA, Mrows, Fn, Dn);
    // 7) out = xres + h @ w2^T + b2   (reads+writes d_out elementwise)
    gemm_nt<1><<<dim3(Dn / 64, Mrows / 64), 256, 0, stream>>>(
        regA, w2, b2, out, out, Mrows, Dn, Fn);
}

// Round 2
// 572.800 us; speedup vs baseline: 2.1524x; 2.1524x over previous
//
#include <hip/hip_runtime.h>
#include <math.h>

// Problem constants
constexpr int Bn = 4;
constexpr int Tn = 2048;
constexpr int Dn = 512;
constexpr int Hn = 8;
constexpr int HDn = 64;       // head dim
constexpr int Fn = 2048;
constexpr int WIN = 128;
constexpr float EPS = 1e-5f;
constexpr int Mrows = Bn * Tn;          // 8192
constexpr int QKVD = 3 * Dn;            // 1536

using short8 = __attribute__((ext_vector_type(8))) short;
using f32x4  = __attribute__((ext_vector_type(4))) float;

// fp32 -> bf16 (RNE) as raw short
__device__ __forceinline__ short f2bf(float f) {
    unsigned u = __float_as_uint(f);
    unsigned r = (u + 0x7FFFu + ((u >> 16) & 1u)) >> 16;
    return (short)r;
}

__device__ __forceinline__ float gelu_exact(float v) {
    return 0.5f * v * (1.0f + erff(v * 0.70710678118654752f));
}

// async 16B global -> LDS (wave-uniform LDS base; HW scatters lane i at base+16*i)
__device__ __forceinline__ void async16(const short* g, short* l) {
    __builtin_amdgcn_global_load_lds(
        (const __attribute__((address_space(1))) void*)g,
        (__attribute__((address_space(3))) void*)l,
        16, 0, 0);
}

// ---------------- fp32 -> bf16 convert (weights) ----------------
__global__ __launch_bounds__(256) void cvt_bf16(const float* __restrict__ src,
                                                short* __restrict__ dst, int n4)
{
    int i = blockIdx.x * 256 + threadIdx.x;
    if (i < n4) {
        float4 v = ((const float4*)src)[i];
        short4 o;
        o.x = f2bf(v.x); o.y = f2bf(v.y); o.z = f2bf(v.z); o.w = f2bf(v.w);
        ((short4*)dst)[i] = o;
    }
}

// ---------------- LayerNorm: one wave per row of 512; bf16 output ----------------
__global__ __launch_bounds__(64) void ln_kernel(const float* __restrict__ x,
                                                const float* __restrict__ g,
                                                const float* __restrict__ b,
                                                short* __restrict__ y)
{
    int row = blockIdx.x;
    int lane = threadIdx.x;
    const float4* xr = (const float4*)(x + (size_t)row * Dn);
    float4 v0 = xr[lane];
    float4 v1 = xr[lane + 64];
    float s = v0.x + v0.y + v0.z + v0.w + v1.x + v1.y + v1.z + v1.w;
#pragma unroll
    for (int off = 32; off >= 1; off >>= 1) s += __shfl_xor(s, off, 64);
    float mu = s * (1.0f / Dn);
    float d0x = v0.x - mu, d0y = v0.y - mu, d0z = v0.z - mu, d0w = v0.w - mu;
    float d1x = v1.x - mu, d1y = v1.y - mu, d1z = v1.z - mu, d1w = v1.w - mu;
    float q = d0x*d0x + d0y*d0y + d0z*d0z + d0w*d0w
            + d1x*d1x + d1y*d1y + d1z*d1z + d1w*d1w;
#pragma unroll
    for (int off = 32; off >= 1; off >>= 1) q += __shfl_xor(q, off, 64);
    float inv = rsqrtf(q * (1.0f / Dn) + EPS);
    const float4* gr = (const float4*)g;
    const float4* br = (const float4*)b;
    float4 g0 = gr[lane], g1 = gr[lane + 64];
    float4 b0 = br[lane], b1 = br[lane + 64];
    short8 o;
    o[0] = f2bf(d0x * inv * g0.x + b0.x);
    o[1] = f2bf(d0y * inv * g0.y + b0.y);
    o[2] = f2bf(d0z * inv * g0.z + b0.z);
    o[3] = f2bf(d0w * inv * g0.w + b0.w);
    o[4] = f2bf(d1x * inv * g1.x + b1.x);
    o[5] = f2bf(d1y * inv * g1.y + b1.y);
    o[6] = f2bf(d1z * inv * g1.z + b1.z);
    o[7] = f2bf(d1w * inv * g1.w + b1.w);
    // interleave: lane writes elements [8*lane .. 8*lane+7)? No — keep row layout:
    // lane covers cols {4*lane..4*lane+3} and {256+4*lane..}; store as two short4.
    short4 a0; a0.x = o[0]; a0.y = o[1]; a0.z = o[2]; a0.w = o[3];
    short4 a1; a1.x = o[4]; a1.y = o[5]; a1.z = o[6]; a1.w = o[7];
    short4* yr = (short4*)(y + (size_t)row * Dn);
    yr[lane] = a0;
    yr[lane + 64] = a1;
}

// ---------------- bf16 MFMA GEMM (NT): C[m,n] = sum_k A[m,k]*Bw[n,k] + bias[n]
// MODE 0: f32 out, bias. MODE 1: f32 out, bias+resid. MODE 2: bf16 out, gelu(bias+..).
// Tile 128x128, BK=32, 4 waves (2x2), each wave 64x64 via 4x4 mfma_16x16x32 frags.
template <int MODE>
__global__ __launch_bounds__(256) void gemm_mfma(const short* __restrict__ A,
                                                 const short* __restrict__ Bw,
                                                 const float* __restrict__ bias,
                                                 const float* __restrict__ resid,
                                                 void* __restrict__ Cout,
                                                 int M, int N, int K)
{
    __shared__ short As[128 * 32];
    __shared__ short Bs[128 * 32];
    int tid = threadIdx.x;
    int w = tid >> 6, lane = tid & 63;
    int wr = w >> 1, wc = w & 1;
    int m0 = blockIdx.y * 128, n0 = blockIdx.x * 128;
    int quad = lane >> 4, l16 = lane & 15;

    f32x4 zero = {0.f, 0.f, 0.f, 0.f};
    f32x4 acc[4][4];
#pragma unroll
    for (int i = 0; i < 4; ++i)
#pragma unroll
        for (int j = 0; j < 4; ++j) acc[i][j] = zero;

    // staging: 8 chunks of 16 rows x 32 cols (1 KB); wave w owns chunks 2w, 2w+1
    int c0 = 2 * w;
    int rowA = lane >> 2;          // 0..15
    int kcol = (lane & 3) * 8;     // 0,8,16,24
    const short* Ag0 = A + (size_t)(m0 + c0 * 16 + rowA) * K + kcol;
    const short* Ag1 = A + (size_t)(m0 + c0 * 16 + 16 + rowA) * K + kcol;
    const short* Bg0 = Bw + (size_t)(n0 + c0 * 16 + rowA) * K + kcol;
    const short* Bg1 = Bw + (size_t)(n0 + c0 * 16 + 16 + rowA) * K + kcol;
    short* Al0 = As + c0 * 512;
    short* Al1 = As + c0 * 512 + 512;
    short* Bl0 = Bs + c0 * 512;
    short* Bl1 = Bs + c0 * 512 + 512;

    for (int kt = 0; kt < K; kt += 32) {
        async16(Ag0 + kt, Al0);
        async16(Ag1 + kt, Al1);
        async16(Bg0 + kt, Bl0);
        async16(Bg1 + kt, Bl1);
        __syncthreads();   // drains vmcnt -> staging complete
        short8 aF[4], bF[4];
#pragma unroll
        for (int i = 0; i < 4; ++i) {
            aF[i] = *(const short8*)(As + (wr * 64 + i * 16 + l16) * 32 + quad * 8);
            bF[i] = *(const short8*)(Bs + (wc * 64 + i * 16 + l16) * 32 + quad * 8);
        }
#pragma unroll
        for (int i = 0; i < 4; ++i)
#pragma unroll
            for (int j = 0; j < 4; ++j)
                acc[i][j] = __builtin_amdgcn_mfma_f32_16x16x32_bf16(
                    aF[i], bF[j], acc[i][j], 0, 0, 0);
        __syncthreads();   // all reads done before next overwrite
    }

    float* Cf = (float*)Cout;
    short* Cb = (short*)Cout;
#pragma unroll
    for (int j = 0; j < 4; ++j) {
        int n = n0 + wc * 64 + j * 16 + l16;
        float bv = bias[n];
#pragma unroll
        for (int i = 0; i < 4; ++i) {
            int mbase = m0 + wr * 64 + i * 16 + quad * 4;
#pragma unroll
            for (int r = 0; r < 4; ++r) {
                size_t idx = (size_t)(mbase + r) * N + n;
                float v = acc[i][j][r] + bv;
                if (MODE == 1) v += resid[idx];
                if (MODE == 2) {
                    Cb[idx] = f2bf(gelu_exact(v));
                } else {
                    Cf[idx] = v;
                }
            }
        }
    }
}

// ---------------- Sliding-window attention: one wave per (b,h,t) query ----------------
// qkv (f32): (B,T,1536), q=[0:512) k=[512:1024) v=[1024:1536); ctx out bf16 (B,T,512)
__global__ __launch_bounds__(256) void attn_kernel(const float* __restrict__ qkv,
                                                   short* __restrict__ ctx)
{
    __shared__ float qs[4][64];
    __shared__ float pb[4][128];
    int wid = threadIdx.x >> 6;
    int lane = threadIdx.x & 63;
    int g = blockIdx.x * 4 + wid;          // ((b*H + h)*T + t)
    int t = g & (Tn - 1);
    int bh = g >> 11;
    int h = bh & (Hn - 1);
    int b = bh >> 3;

    const float* qrow = qkv + ((size_t)(b * Tn + t)) * QKVD + h * HDn;
    qs[wid][lane] = qrow[lane];
    __syncthreads();

    int lo = t - (WIN - 1); if (lo < 0) lo = 0;
    int L = t - lo + 1;
    int j0 = lo + lane, j1 = lo + 64 + lane;
    bool ok0 = (j0 <= t), ok1 = (j1 <= t);
    float s0 = -INFINITY, s1 = -INFINITY;
    if (ok0) {
        const float4* kp = (const float4*)(qkv + ((size_t)(b * Tn + j0)) * QKVD + Dn + h * HDn);
        float acc = 0.f;
#pragma unroll
        for (int d4 = 0; d4 < 16; ++d4) {
            float4 kv = kp[d4];
            acc += qs[wid][4 * d4 + 0] * kv.x + qs[wid][4 * d4 + 1] * kv.y
                 + qs[wid][4 * d4 + 2] * kv.z + qs[wid][4 * d4 + 3] * kv.w;
        }
        s0 = acc * 0.125f;
    }
    if (ok1) {
        const float4* kp = (const float4*)(qkv + ((size_t)(b * Tn + j1)) * QKVD + Dn + h * HDn);
        float acc = 0.f;
#pragma unroll
        for (int d4 = 0; d4 < 16; ++d4) {
            float4 kv = kp[d4];
            acc += qs[wid][4 * d4 + 0] * kv.x + qs[wid][4 * d4 + 1] * kv.y
                 + qs[wid][4 * d4 + 2] * kv.z + qs[wid][4 * d4 + 3] * kv.w;
        }
        s1 = acc * 0.125f;
    }
    float m = fmaxf(s0, s1);
#pragma unroll
    for (int off = 32; off >= 1; off >>= 1) m = fmaxf(m, __shfl_xor(m, off, 64));
    float p0 = ok0 ? expf(s0 - m) : 0.f;
    float p1 = ok1 ? expf(s1 - m) : 0.f;
    float den = p0 + p1;
#pragma unroll
    for (int off = 32; off >= 1; off >>= 1) den += __shfl_xor(den, off, 64);
    float inv = 1.0f / den;
    pb[wid][lane] = p0;
    pb[wid][64 + lane] = p1;
    __syncthreads();

    float acc = 0.f;
    const float* vp = qkv + ((size_t)(b * Tn + lo)) * QKVD + 2 * Dn + h * HDn + lane;
    for (int j = 0; j < L; ++j) acc += pb[wid][j] * vp[(size_t)j * QKVD];
    ctx[((size_t)(b * Tn + t)) * Dn + h * HDn + lane] = f2bf(acc * inv);
}

extern "C" void kernel_launch(void* const* d_in, const int* in_sizes, int n_in,
                              void* d_out, int out_size, void* d_ws, size_t ws_size,
                              hipStream_t stream)
{
    const float* x         = (const float*)d_in[0];
    const float* in_proj_w = (const float*)d_in[1];
    const float* in_proj_b = (const float*)d_in[2];
    const float* out_w     = (const float*)d_in[3];
    const float* out_b     = (const float*)d_in[4];
    const float* ln1_g     = (const float*)d_in[5];
    const float* ln1_b     = (const float*)d_in[6];
    const float* ln2_g     = (const float*)d_in[7];
    const float* ln2_b     = (const float*)d_in[8];
    const float* w1        = (const float*)d_in[9];
    const float* b1        = (const float*)d_in[10];
    const float* w2        = (const float*)d_in[11];
    const float* b2        = (const float*)d_in[12];
    float* out = (float*)d_out;

    // Workspace (<= 62 MB):
    //   regA @ 0      : 48 MB  — qkv f32 (B,T,1536), later h bf16 (B,T,2048)=32MB
    //   regB @ 48 MB  :  8 MB  — x2/ctx/x3 bf16 (B,T,512)
    //   wts  @ 56 MB  :  6 MB  — bf16 weights
    char* ws = (char*)d_ws;
    float* regA_f = (float*)ws;
    short* regA_h = (short*)ws;
    short* regB   = (short*)(ws + (size_t)48 * 1024 * 1024);
    short* wq  = (short*)(ws + (size_t)56 * 1024 * 1024);
    short* wo  = wq + (size_t)QKVD * Dn;       // 786432
    short* w1b = wo + (size_t)Dn * Dn;         // +262144
    short* w2b = w1b + (size_t)Fn * Dn;        // +1048576

    // weight conversion (every call; ws is re-poisoned between timed calls)
    cvt_bf16<<<(QKVD * Dn / 4 + 255) / 256, 256, 0, stream>>>(in_proj_w, wq, QKVD * Dn / 4);
    cvt_bf16<<<(Dn * Dn / 4 + 255) / 256, 256, 0, stream>>>(out_w, wo, Dn * Dn / 4);
    cvt_bf16<<<(Fn * Dn / 4 + 255) / 256, 256, 0, stream>>>(w1, w1b, Fn * Dn / 4);
    cvt_bf16<<<(Dn * Fn / 4 + 255) / 256, 256, 0, stream>>>(w2, w2b, Dn * Fn / 4);

    // 1) x2 = LN1(x)  -> bf16
    ln_kernel<<<Mrows, 64, 0, stream>>>(x, ln1_g, ln1_b, regB);
    // 2) qkv = x2 @ in_proj_w^T + b  -> f32
    gemm_mfma<0><<<dim3(QKVD / 128, Mrows / 128), 256, 0, stream>>>(
        regB, wq, in_proj_b, nullptr, regA_f, Mrows, QKVD, Dn);
    // 3) ctx = attention(qkv) -> bf16
    attn_kernel<<<(Bn * Hn * Tn) / 4, 256, 0, stream>>>(regA_f, regB);
    // 4) out = x + ctx @ out_w^T + out_b  -> f32 in d_out
    gemm_mfma<1><<<dim3(Dn / 128, Mrows / 128), 256, 0, stream>>>(
        regB, wo, out_b, x, out, Mrows, Dn, Dn);
    // 5) x3 = LN2(out) -> bf16
    ln_kernel<<<Mrows, 64, 0, stream>>>(out, ln2_g, ln2_b, regB);
    // 6) h = gelu(x3 @ w1^T + b1) -> bf16
    gemm_mfma<2><<<dim3(Fn / 128, Mrows / 128), 256, 0, stream>>>(
        regB, w1b, b1, nullptr, regA_h, Mrows, Fn, Dn);
    // 7) out = out + h @ w2^T + b2 -> f32
    gemm_mfma<1><<<dim3(Dn / 128, Mrows / 128), 256, 0, stream>>>(
        regA_h, w2b, b2, out, out, Mrows, Dn, Fn);
}

// Round 3
// 266.964 us; speedup vs baseline: 4.6183x; 2.1456x over previous
//
#include <hip/hip_runtime.h>
#include <math.h>

// Problem constants
constexpr int Bn = 4;
constexpr int Tn = 2048;
constexpr int Dn = 512;
constexpr int Hn = 8;
constexpr int HDn = 64;       // head dim
constexpr int Fn = 2048;
constexpr int WIN = 128;
constexpr float EPS = 1e-5f;
constexpr int Mrows = Bn * Tn;          // 8192
constexpr int QKVD = 3 * Dn;            // 1536

using short8 = __attribute__((ext_vector_type(8))) short;
using f32x4  = __attribute__((ext_vector_type(4))) float;

// fp32 -> bf16 (RNE) as raw short
__device__ __forceinline__ short f2bf(float f) {
    unsigned u = __float_as_uint(f);
    unsigned r = (u + 0x7FFFu + ((u >> 16) & 1u)) >> 16;
    return (short)r;
}

__device__ __forceinline__ float gelu_exact(float v) {
    return 0.5f * v * (1.0f + erff(v * 0.70710678118654752f));
}

// async 16B global -> LDS (wave-uniform LDS base; HW scatters lane i at base+16*i)
__device__ __forceinline__ void async16(const short* g, short* l) {
    __builtin_amdgcn_global_load_lds(
        (const __attribute__((address_space(1))) void*)g,
        (__attribute__((address_space(3))) void*)l,
        16, 0, 0);
}

// ---------------- fp32 -> bf16 convert (weights) ----------------
__global__ __launch_bounds__(256) void cvt_bf16(const float* __restrict__ src,
                                                short* __restrict__ dst, int n4)
{
    int i = blockIdx.x * 256 + threadIdx.x;
    if (i < n4) {
        float4 v = ((const float4*)src)[i];
        short4 o;
        o.x = f2bf(v.x); o.y = f2bf(v.y); o.z = f2bf(v.z); o.w = f2bf(v.w);
        ((short4*)dst)[i] = o;
    }
}

// ---------------- LayerNorm: one wave per row of 512; bf16 output ----------------
__global__ __launch_bounds__(64) void ln_kernel(const float* __restrict__ x,
                                                const float* __restrict__ g,
                                                const float* __restrict__ b,
                                                short* __restrict__ y)
{
    int row = blockIdx.x;
    int lane = threadIdx.x;
    const float4* xr = (const float4*)(x + (size_t)row * Dn);
    float4 v0 = xr[lane];
    float4 v1 = xr[lane + 64];
    float s = v0.x + v0.y + v0.z + v0.w + v1.x + v1.y + v1.z + v1.w;
#pragma unroll
    for (int off = 32; off >= 1; off >>= 1) s += __shfl_xor(s, off, 64);
    float mu = s * (1.0f / Dn);
    float d0x = v0.x - mu, d0y = v0.y - mu, d0z = v0.z - mu, d0w = v0.w - mu;
    float d1x = v1.x - mu, d1y = v1.y - mu, d1z = v1.z - mu, d1w = v1.w - mu;
    float q = d0x*d0x + d0y*d0y + d0z*d0z + d0w*d0w
            + d1x*d1x + d1y*d1y + d1z*d1z + d1w*d1w;
#pragma unroll
    for (int off = 32; off >= 1; off >>= 1) q += __shfl_xor(q, off, 64);
    float inv = rsqrtf(q * (1.0f / Dn) + EPS);
    const float4* gr = (const float4*)g;
    const float4* br = (const float4*)b;
    float4 g0 = gr[lane], g1 = gr[lane + 64];
    float4 b0 = br[lane], b1 = br[lane + 64];
    short4 a0, a1;
    a0.x = f2bf(d0x * inv * g0.x + b0.x);
    a0.y = f2bf(d0y * inv * g0.y + b0.y);
    a0.z = f2bf(d0z * inv * g0.z + b0.z);
    a0.w = f2bf(d0w * inv * g0.w + b0.w);
    a1.x = f2bf(d1x * inv * g1.x + b1.x);
    a1.y = f2bf(d1y * inv * g1.y + b1.y);
    a1.z = f2bf(d1z * inv * g1.z + b1.z);
    a1.w = f2bf(d1w * inv * g1.w + b1.w);
    short4* yr = (short4*)(y + (size_t)row * Dn);
    yr[lane] = a0;
    yr[lane + 64] = a1;
}

// ---------------- bf16 MFMA GEMM (NT): C[m,n] = sum_k A[m,k]*Bw[n,k] + bias[n]
// MODE 0: f32 out + bias. MODE 1: f32 out + bias + resid. MODE 2: bf16 out, gelu.
// MODE 3: bf16 out scattered into attention layouts (q/k row-major, v transposed).
// Tile 128x128, BK=32, 4 waves (2x2), each wave 64x64 via 4x4 mfma_16x16x32 frags.
template <int MODE>
__global__ __launch_bounds__(256) void gemm_mfma(const short* __restrict__ A,
                                                 const short* __restrict__ Bw,
                                                 const float* __restrict__ bias,
                                                 const float* __restrict__ resid,
                                                 void* __restrict__ Cout,
                                                 short* __restrict__ q_out,
                                                 short* __restrict__ k_out,
                                                 short* __restrict__ v_out,
                                                 int M, int N, int K)
{
    __shared__ short As[128 * 32];
    __shared__ short Bs[128 * 32];
    int tid = threadIdx.x;
    int w = tid >> 6, lane = tid & 63;
    int wr = w >> 1, wc = w & 1;
    int m0 = blockIdx.y * 128, n0 = blockIdx.x * 128;
    int quad = lane >> 4, l16 = lane & 15;

    f32x4 zero = {0.f, 0.f, 0.f, 0.f};
    f32x4 acc[4][4];
#pragma unroll
    for (int i = 0; i < 4; ++i)
#pragma unroll
        for (int j = 0; j < 4; ++j) acc[i][j] = zero;

    int c0 = 2 * w;
    int rowA = lane >> 2;
    int kcol = (lane & 3) * 8;
    const short* Ag0 = A + (size_t)(m0 + c0 * 16 + rowA) * K + kcol;
    const short* Ag1 = A + (size_t)(m0 + c0 * 16 + 16 + rowA) * K + kcol;
    const short* Bg0 = Bw + (size_t)(n0 + c0 * 16 + rowA) * K + kcol;
    const short* Bg1 = Bw + (size_t)(n0 + c0 * 16 + 16 + rowA) * K + kcol;
    short* Al0 = As + c0 * 512;
    short* Al1 = As + c0 * 512 + 512;
    short* Bl0 = Bs + c0 * 512;
    short* Bl1 = Bs + c0 * 512 + 512;

    for (int kt = 0; kt < K; kt += 32) {
        async16(Ag0 + kt, Al0);
        async16(Ag1 + kt, Al1);
        async16(Bg0 + kt, Bl0);
        async16(Bg1 + kt, Bl1);
        __syncthreads();
        short8 aF[4], bF[4];
#pragma unroll
        for (int i = 0; i < 4; ++i) {
            aF[i] = *(const short8*)(As + (wr * 64 + i * 16 + l16) * 32 + quad * 8);
            bF[i] = *(const short8*)(Bs + (wc * 64 + i * 16 + l16) * 32 + quad * 8);
        }
#pragma unroll
        for (int i = 0; i < 4; ++i)
#pragma unroll
            for (int j = 0; j < 4; ++j)
                acc[i][j] = __builtin_amdgcn_mfma_f32_16x16x32_bf16(
                    aF[i], bF[j], acc[i][j], 0, 0, 0);
        __syncthreads();
    }

    if (MODE == 3) {
        int b = m0 >> 11;
#pragma unroll
        for (int j = 0; j < 4; ++j) {
            int n = n0 + wc * 64 + j * 16 + l16;
            float bv = bias[n];
            int sec = n >> 9;            // 0=q 1=k 2=v (uniform per j)
            int nn = n & 511;
            int h = nn >> 6, d = nn & 63;
            int bh = b * 8 + h;
#pragma unroll
            for (int i = 0; i < 4; ++i) {
                int mbase = m0 + wr * 64 + i * 16 + quad * 4;
                int t0 = mbase & 2047;
                if (sec == 2) {
                    short4 pk;
                    pk.x = f2bf(acc[i][j][0] + bv);
                    pk.y = f2bf(acc[i][j][1] + bv);
                    pk.z = f2bf(acc[i][j][2] + bv);
                    pk.w = f2bf(acc[i][j][3] + bv);
                    *(short4*)(v_out + ((size_t)(bh * 64 + d)) * 2048 + t0) = pk;
                } else {
                    short* dst = (sec == 0 ? q_out : k_out)
                               + ((size_t)bh * 2048 + t0) * 64 + d;
#pragma unroll
                    for (int r = 0; r < 4; ++r)
                        dst[(size_t)r * 64] = f2bf(acc[i][j][r] + bv);
                }
            }
        }
        return;
    }

    float* Cf = (float*)Cout;
    short* Cb = (short*)Cout;
#pragma unroll
    for (int j = 0; j < 4; ++j) {
        int n = n0 + wc * 64 + j * 16 + l16;
        float bv = bias[n];
#pragma unroll
        for (int i = 0; i < 4; ++i) {
            int mbase = m0 + wr * 64 + i * 16 + quad * 4;
#pragma unroll
            for (int r = 0; r < 4; ++r) {
                size_t idx = (size_t)(mbase + r) * N + n;
                float v = acc[i][j][r] + bv;
                if (MODE == 1) v += resid[idx];
                if (MODE == 2) {
                    Cb[idx] = f2bf(gelu_exact(v));
                } else {
                    Cf[idx] = v;
                }
            }
        }
    }
}

// ---------------- MFMA sliding-window attention ----------------
// One block: one (b,h), 64-query tile. Keys [q0-128, q0+64) = 192.
// Qg/Kg: [bh][t][64] bf16; Vtg: [bh][64][2048] bf16 (dim-major). ctx: (B,T,512) bf16.
constexpr int QS = 72;    // Qs/Ks LDS row stride (shorts): 144B = 9x16B
constexpr int VS = 200;   // Vt/Ps LDS row stride (shorts): 400B = 25x16B

__global__ __launch_bounds__(256) void attn_mfma(const short* __restrict__ Qg,
                                                 const short* __restrict__ Kg,
                                                 const short* __restrict__ Vtg,
                                                 short* __restrict__ ctx)
{
    __shared__ short Qs[64 * QS];      // 4608 shorts
    __shared__ short Ks[192 * QS];     // 13824 shorts; aliased as Ps[64*VS]=12800 later
    __shared__ short Vt[64 * VS];      // 12800 shorts
    int tid = threadIdx.x;
    int w = tid >> 6, lane = tid & 63, quad = lane >> 4, l16 = lane & 15;
    int blk = blockIdx.x;
    int q0 = (blk & 31) << 6;
    int bh = blk >> 5;
    int kbase = q0 - 128;

    // stage Q: 64 rows x 64 shorts (8 chunks of 16B each)
    {
        const short* src = Qg + ((size_t)bh * 2048 + q0) * 64;
        for (int c = tid; c < 512; c += 256) {
            int row = c >> 3, off = (c & 7) * 8;
            *(short8*)(Qs + row * QS + off) = *(const short8*)(src + row * 64 + off);
        }
    }
    // stage K: 192 rows (clamped to valid t)
    {
        const short* base = Kg + (size_t)bh * 2048 * 64;
        for (int c = tid; c < 1536; c += 256) {
            int row = c >> 3, off = (c & 7) * 8;
            int srow = kbase + row; srow = srow < 0 ? 0 : srow;
            *(short8*)(Ks + row * QS + off) = *(const short8*)(base + (size_t)srow * 64 + off);
        }
    }
    // stage Vt: 64 dim-rows x 192 keys (24 chunks), clamp chunk start
    {
        const short* base = Vtg + (size_t)bh * 64 * 2048;
        for (int c = tid; c < 1536; c += 256) {
            int row = c / 24, cc = c - row * 24;
            int off = cc * 8;
            int scol = kbase + off; scol = scol < 0 ? 0 : scol;
            *(short8*)(Vt + row * VS + off) = *(const short8*)(base + (size_t)row * 2048 + scol);
        }
    }
    __syncthreads();

    // S = Q K^T  (wave w: queries w*16..+15, all 192 keys -> 12 tiles)
    short8 aF0 = *(const short8*)(Qs + (w * 16 + l16) * QS + quad * 8);
    short8 aF1 = *(const short8*)(Qs + (w * 16 + l16) * QS + 32 + quad * 8);
    f32x4 S[12];
    f32x4 zero = {0.f, 0.f, 0.f, 0.f};
#pragma unroll
    for (int t = 0; t < 12; ++t) S[t] = zero;
#pragma unroll
    for (int t = 0; t < 12; ++t) {
        short8 b0 = *(const short8*)(Ks + (t * 16 + l16) * QS + quad * 8);
        short8 b1 = *(const short8*)(Ks + (t * 16 + l16) * QS + 32 + quad * 8);
        S[t] = __builtin_amdgcn_mfma_f32_16x16x32_bf16(aF0, b0, S[t], 0, 0, 0);
        S[t] = __builtin_amdgcn_mfma_f32_16x16x32_bf16(aF1, b1, S[t], 0, 0, 0);
    }

    // mask + softmax (rows i_local = w*16 + quad*4 + r)
    int i0 = w * 16 + quad * 4;
    float mrow[4] = {-INFINITY, -INFINITY, -INFINITY, -INFINITY};
#pragma unroll
    for (int t = 0; t < 12; ++t) {
        int jl = t * 16 + l16;
        int kg = kbase + jl;
#pragma unroll
        for (int r = 0; r < 4; ++r) {
            int dj = jl - (i0 + r);
            bool ok = (dj >= 1) && (dj <= 128) && (kg >= 0);
            float s = ok ? S[t][r] * 0.125f : -INFINITY;
            S[t][r] = s;
            mrow[r] = fmaxf(mrow[r], s);
        }
    }
#pragma unroll
    for (int off = 8; off >= 1; off >>= 1)
#pragma unroll
        for (int r = 0; r < 4; ++r)
            mrow[r] = fmaxf(mrow[r], __shfl_xor(mrow[r], off, 64));
    float sum[4] = {0.f, 0.f, 0.f, 0.f};
#pragma unroll
    for (int t = 0; t < 12; ++t)
#pragma unroll
        for (int r = 0; r < 4; ++r) {
            float p = __expf(S[t][r] - mrow[r]);
            S[t][r] = p;
            sum[r] += p;
        }
#pragma unroll
    for (int off = 8; off >= 1; off >>= 1)
#pragma unroll
        for (int r = 0; r < 4; ++r)
            sum[r] += __shfl_xor(sum[r], off, 64);
    float inv[4];
#pragma unroll
    for (int r = 0; r < 4; ++r) inv[r] = 1.0f / sum[r];

    __syncthreads();            // all waves done reading Ks -> alias as Ps
    short* Ps = Ks;
#pragma unroll
    for (int t = 0; t < 12; ++t)
#pragma unroll
        for (int r = 0; r < 4; ++r)
            Ps[(w * 16 + quad * 4 + r) * VS + t * 16 + l16] = f2bf(S[t][r]);
    // same-wave write->read: compiler inserts lgkmcnt wait; no barrier needed

    f32x4 O[4];
#pragma unroll
    for (int tN = 0; tN < 4; ++tN) O[tN] = zero;
#pragma unroll
    for (int s = 0; s < 6; ++s) {
        short8 aP = *(const short8*)(Ps + (w * 16 + l16) * VS + s * 32 + quad * 8);
#pragma unroll
        for (int tN = 0; tN < 4; ++tN) {
            short8 bV = *(const short8*)(Vt + (tN * 16 + l16) * VS + s * 32 + quad * 8);
            O[tN] = __builtin_amdgcn_mfma_f32_16x16x32_bf16(aP, bV, O[tN], 0, 0, 0);
        }
    }

    int b = bh >> 3, h = bh & 7;
#pragma unroll
    for (int tN = 0; tN < 4; ++tN)
#pragma unroll
        for (int r = 0; r < 4; ++r) {
            int trow = q0 + w * 16 + quad * 4 + r;
            ctx[((size_t)(b * 2048 + trow)) * 512 + h * 64 + tN * 16 + l16] =
                f2bf(O[tN][r] * inv[r]);
        }
}

extern "C" void kernel_launch(void* const* d_in, const int* in_sizes, int n_in,
                              void* d_out, int out_size, void* d_ws, size_t ws_size,
                              hipStream_t stream)
{
    const float* x         = (const float*)d_in[0];
    const float* in_proj_w = (const float*)d_in[1];
    const float* in_proj_b = (const float*)d_in[2];
    const float* out_w     = (const float*)d_in[3];
    const float* out_b     = (const float*)d_in[4];
    const float* ln1_g     = (const float*)d_in[5];
    const float* ln1_b     = (const float*)d_in[6];
    const float* ln2_g     = (const float*)d_in[7];
    const float* ln2_b     = (const float*)d_in[8];
    const float* w1        = (const float*)d_in[9];
    const float* b1        = (const float*)d_in[10];
    const float* w2        = (const float*)d_in[11];
    const float* b2        = (const float*)d_in[12];
    float* out = (float*)d_out;

    // Workspace (46.3 MB):
    //   attnQ @ 0     : 8 MB   [bh][t][64] bf16      \
    //   attnK @ 8 MB  : 8 MB   [bh][t][64] bf16       }- dead after attention;
    //   attnV @ 16 MB : 8 MB   [bh][64][2048] bf16   /   h (32MB) overlays 0..32MB
    //   regB  @ 32 MB : 8 MB   x2/ctx/x3 bf16 (B,T,512)
    //   wts   @ 40 MB : 6.3 MB bf16 weights
    char* ws = (char*)d_ws;
    short* attnQ = (short*)ws;
    short* attnK = (short*)(ws + (size_t)8 * 1024 * 1024);
    short* attnV = (short*)(ws + (size_t)16 * 1024 * 1024);
    short* hbuf  = (short*)ws;                                  // overlays attnQKV
    short* regB  = (short*)(ws + (size_t)32 * 1024 * 1024);
    short* wq  = (short*)(ws + (size_t)40 * 1024 * 1024);
    short* wo  = wq + (size_t)QKVD * Dn;
    short* w1b = wo + (size_t)Dn * Dn;
    short* w2b = w1b + (size_t)Fn * Dn;

    cvt_bf16<<<(QKVD * Dn / 4 + 255) / 256, 256, 0, stream>>>(in_proj_w, wq, QKVD * Dn / 4);
    cvt_bf16<<<(Dn * Dn / 4 + 255) / 256, 256, 0, stream>>>(out_w, wo, Dn * Dn / 4);
    cvt_bf16<<<(Fn * Dn / 4 + 255) / 256, 256, 0, stream>>>(w1, w1b, Fn * Dn / 4);
    cvt_bf16<<<(Dn * Fn / 4 + 255) / 256, 256, 0, stream>>>(w2, w2b, Dn * Fn / 4);

    // 1) x2 = LN1(x) -> bf16
    ln_kernel<<<Mrows, 64, 0, stream>>>(x, ln1_g, ln1_b, regB);
    // 2) qkv = x2 @ in_proj_w^T + b -> bf16 attention layouts
    gemm_mfma<3><<<dim3(QKVD / 128, Mrows / 128), 256, 0, stream>>>(
        regB, wq, in_proj_b, nullptr, nullptr, attnQ, attnK, attnV, Mrows, QKVD, Dn);
    // 3) ctx = attention -> bf16 (B,T,512)
    attn_mfma<<<Bn * Hn * (Tn / 64), 256, 0, stream>>>(attnQ, attnK, attnV, regB);
    // 4) out = x + ctx @ out_w^T + out_b -> f32
    gemm_mfma<1><<<dim3(Dn / 128, Mrows / 128), 256, 0, stream>>>(
        regB, wo, out_b, x, out, nullptr, nullptr, nullptr, Mrows, Dn, Dn);
    // 5) x3 = LN2(out) -> bf16
    ln_kernel<<<Mrows, 64, 0, stream>>>(out, ln2_g, ln2_b, regB);
    // 6) h = gelu(x3 @ w1^T + b1) -> bf16 (overlays dead attn buffers)
    gemm_mfma<2><<<dim3(Fn / 128, Mrows / 128), 256, 0, stream>>>(
        regB, w1b, b1, nullptr, hbuf, nullptr, nullptr, nullptr, Mrows, Fn, Dn);
    // 7) out = out + h @ w2^T + b2 -> f32
    gemm_mfma<1><<<dim3(Dn / 128, Mrows / 128), 256, 0, stream>>>(
        hbuf, w2b, b2, out, out, nullptr, nullptr, nullptr, Mrows, Dn, Fn);
}

// Round 4
// 260.287 us; speedup vs baseline: 4.7367x; 1.0257x over previous
//
#include <hip/hip_runtime.h>
#include <math.h>

// Problem constants
constexpr int Bn = 4;
constexpr int Tn = 2048;
constexpr int Dn = 512;
constexpr int Hn = 8;
constexpr int HDn = 64;       // head dim
constexpr int Fn = 2048;
constexpr int WIN = 128;
constexpr float EPS = 1e-5f;
constexpr int Mrows = Bn * Tn;          // 8192
constexpr int QKVD = 3 * Dn;            // 1536

using short8 = __attribute__((ext_vector_type(8))) short;
using f32x4  = __attribute__((ext_vector_type(4))) float;

// fp32 -> bf16 (RNE) as raw short
__device__ __forceinline__ short f2bf(float f) {
    unsigned u = __float_as_uint(f);
    unsigned r = (u + 0x7FFFu + ((u >> 16) & 1u)) >> 16;
    return (short)r;
}

__device__ __forceinline__ float gelu_exact(float v) {
    return 0.5f * v * (1.0f + erff(v * 0.70710678118654752f));
}

// async 16B global -> LDS (wave-uniform LDS base; HW scatters lane i at base+16*i)
__device__ __forceinline__ void async16(const short* g, short* l) {
    __builtin_amdgcn_global_load_lds(
        (const __attribute__((address_space(1))) void*)g,
        (__attribute__((address_space(3))) void*)l,
        16, 0, 0);
}

// ---------------- fp32 -> bf16 convert (weights) ----------------
__global__ __launch_bounds__(256) void cvt_bf16(const float* __restrict__ src,
                                                short* __restrict__ dst, int n4)
{
    int i = blockIdx.x * 256 + threadIdx.x;
    if (i < n4) {
        float4 v = ((const float4*)src)[i];
        short4 o;
        o.x = f2bf(v.x); o.y = f2bf(v.y); o.z = f2bf(v.z); o.w = f2bf(v.w);
        ((short4*)dst)[i] = o;
    }
}

// ---------------- LayerNorm: one wave per row of 512; bf16 output ----------------
__global__ __launch_bounds__(64) void ln_kernel(const float* __restrict__ x,
                                                const float* __restrict__ g,
                                                const float* __restrict__ b,
                                                short* __restrict__ y)
{
    int row = blockIdx.x;
    int lane = threadIdx.x;
    const float4* xr = (const float4*)(x + (size_t)row * Dn);
    float4 v0 = xr[lane];
    float4 v1 = xr[lane + 64];
    float s = v0.x + v0.y + v0.z + v0.w + v1.x + v1.y + v1.z + v1.w;
#pragma unroll
    for (int off = 32; off >= 1; off >>= 1) s += __shfl_xor(s, off, 64);
    float mu = s * (1.0f / Dn);
    float d0x = v0.x - mu, d0y = v0.y - mu, d0z = v0.z - mu, d0w = v0.w - mu;
    float d1x = v1.x - mu, d1y = v1.y - mu, d1z = v1.z - mu, d1w = v1.w - mu;
    float q = d0x*d0x + d0y*d0y + d0z*d0z + d0w*d0w
            + d1x*d1x + d1y*d1y + d1z*d1z + d1w*d1w;
#pragma unroll
    for (int off = 32; off >= 1; off >>= 1) q += __shfl_xor(q, off, 64);
    float inv = rsqrtf(q * (1.0f / Dn) + EPS);
    const float4* gr = (const float4*)g;
    const float4* br = (const float4*)b;
    float4 g0 = gr[lane], g1 = gr[lane + 64];
    float4 b0 = br[lane], b1 = br[lane + 64];
    short4 a0, a1;
    a0.x = f2bf(d0x * inv * g0.x + b0.x);
    a0.y = f2bf(d0y * inv * g0.y + b0.y);
    a0.z = f2bf(d0z * inv * g0.z + b0.z);
    a0.w = f2bf(d0w * inv * g0.w + b0.w);
    a1.x = f2bf(d1x * inv * g1.x + b1.x);
    a1.y = f2bf(d1y * inv * g1.y + b1.y);
    a1.z = f2bf(d1z * inv * g1.z + b1.z);
    a1.w = f2bf(d1w * inv * g1.w + b1.w);
    short4* yr = (short4*)(y + (size_t)row * Dn);
    yr[lane] = a0;
    yr[lane + 64] = a1;
}

// ---------------- bf16 MFMA GEMM (NT), double-buffered, swizzled LDS ----------------
// C[m,n] = sum_k A[m,k]*Bw[n,k] + bias[n]
// MODE 1: f32 out + bias + resid. MODE 2: bf16 out, gelu(bias+acc).
// MODE 3: bf16 out into attention layouts via LDS repack (q/k row-major, v transposed).
// Tile 128x128, BK=32, 4 waves (2x2), each wave 64x64 via 4x4 mfma_16x16x32 frags.
// LDS chunk swizzle: LDS slot (row, c4) holds global k-chunk (c4 ^ (row&3)) of row.
template <int MODE>
__global__ __launch_bounds__(256) void gemm_mfma(const short* __restrict__ A,
                                                 const short* __restrict__ Bw,
                                                 const float* __restrict__ bias,
                                                 const float* __restrict__ resid,
                                                 void* __restrict__ Cout,
                                                 short* __restrict__ q_out,
                                                 short* __restrict__ k_out,
                                                 short* __restrict__ v_out,
                                                 int M, int N, int K)
{
    __shared__ short As[2][128 * 32];
    __shared__ short Bs[2][128 * 32];
    int tid = threadIdx.x;
    int w = tid >> 6, lane = tid & 63;
    int wr = w >> 1, wc = w & 1;
    int m0 = blockIdx.y * 128, n0 = blockIdx.x * 128;
    int quad = lane >> 4, l16 = lane & 15;

    f32x4 zero = {0.f, 0.f, 0.f, 0.f};
    f32x4 acc[4][4];
#pragma unroll
    for (int i = 0; i < 4; ++i)
#pragma unroll
        for (int j = 0; j < 4; ++j) acc[i][j] = zero;

    int c0 = 2 * w;
    int rowA = lane >> 2;                    // 0..15
    int c4 = lane & 3;
    int kcolS = (c4 ^ (rowA & 3)) * 8;       // swizzled global k-chunk
    const short* AgA = A + (size_t)(m0 + c0 * 16 + rowA) * K + kcolS;
    const short* AgB = A + (size_t)(m0 + c0 * 16 + 16 + rowA) * K + kcolS;
    const short* BgA = Bw + (size_t)(n0 + c0 * 16 + rowA) * K + kcolS;
    const short* BgB = Bw + (size_t)(n0 + c0 * 16 + 16 + rowA) * K + kcolS;

    auto stage = [&](int kt, int pp) {
        async16(AgA + kt, As[pp] + c0 * 512);
        async16(AgB + kt, As[pp] + c0 * 512 + 512);
        async16(BgA + kt, Bs[pp] + c0 * 512);
        async16(BgB + kt, Bs[pp] + c0 * 512 + 512);
    };

    stage(0, 0);
    int p = 0;
    for (int kt = 0; kt < K; kt += 32) {
        __syncthreads();                   // drains my vmcnt -> buf[p] staged; prior reads done
        if (kt + 32 < K) stage(kt + 32, p ^ 1);   // prefetch overlaps the MFMA below
        short8 aF[4], bF[4];
#pragma unroll
        for (int i = 0; i < 4; ++i) {
            int ra = wr * 64 + i * 16 + l16;       // ra&3 == l16&3
            int rb = wc * 64 + i * 16 + l16;
            aF[i] = *(const short8*)(As[p] + ra * 32 + ((quad ^ (l16 & 3)) * 8));
            bF[i] = *(const short8*)(Bs[p] + rb * 32 + ((quad ^ (l16 & 3)) * 8));
        }
#pragma unroll
        for (int i = 0; i < 4; ++i)
#pragma unroll
            for (int j = 0; j < 4; ++j)
                acc[i][j] = __builtin_amdgcn_mfma_f32_16x16x32_bf16(
                    aF[i], bF[j], acc[i][j], 0, 0, 0);
        p ^= 1;
    }

    if constexpr (MODE == 3) {
        // Per-wave 64x64 tile = one head's full d-range for 64 t values.
        __shared__ short Rep[4][64 * 68];
        short* rp = Rep[w];
        int b = m0 >> 11;
        int ncol0 = n0 + wc * 64;
        int sec = ncol0 >> 9;                 // 0=q 1=k 2=v
        int h = (ncol0 & 511) >> 6;
        int bh = b * 8 + h;
        int t0 = (m0 & 2047) + wr * 64;
        if (sec == 2) {
            // transposed into Rep: rp[d*68 + t_local]
#pragma unroll
            for (int j = 0; j < 4; ++j) {
                int d = j * 16 + l16;
                float bv = bias[ncol0 + j * 16 + l16];
#pragma unroll
                for (int i = 0; i < 4; ++i)
#pragma unroll
                    for (int r = 0; r < 4; ++r)
                        rp[d * 68 + i * 16 + quad * 4 + r] = f2bf(acc[i][j][r] + bv);
            }
#pragma unroll
            for (int it = 0; it < 8; ++it) {
                int row = it * 8 + (lane >> 3);        // d
                int off = (lane & 7) * 8;              // t chunk
                *(short8*)(v_out + ((size_t)bh * 64 + row) * 2048 + t0 + off) =
                    *(const short8*)(rp + row * 68 + off);
            }
        } else {
            short* dst = (sec == 0 ? q_out : k_out);
#pragma unroll
            for (int j = 0; j < 4; ++j) {
                int d = j * 16 + l16;
                float bv = bias[ncol0 + j * 16 + l16];
#pragma unroll
                for (int i = 0; i < 4; ++i)
#pragma unroll
                    for (int r = 0; r < 4; ++r)
                        rp[(i * 16 + quad * 4 + r) * 68 + d] = f2bf(acc[i][j][r] + bv);
            }
#pragma unroll
            for (int it = 0; it < 8; ++it) {
                int row = it * 8 + (lane >> 3);        // t_local
                int off = (lane & 7) * 8;              // d chunk
                *(short8*)(dst + ((size_t)bh * 2048 + t0 + row) * 64 + off) =
                    *(const short8*)(rp + row * 68 + off);
            }
        }
        return;
    }

    float* Cf = (float*)Cout;
    short* Cb = (short*)Cout;
#pragma unroll
    for (int j = 0; j < 4; ++j) {
        int n = n0 + wc * 64 + j * 16 + l16;
        float bv = bias[n];
#pragma unroll
        for (int i = 0; i < 4; ++i) {
            int mbase = m0 + wr * 64 + i * 16 + quad * 4;
#pragma unroll
            for (int r = 0; r < 4; ++r) {
                size_t idx = (size_t)(mbase + r) * N + n;
                float v = acc[i][j][r] + bv;
                if (MODE == 1) v += resid[idx];
                if (MODE == 2) {
                    Cb[idx] = f2bf(gelu_exact(v));
                } else {
                    Cf[idx] = v;
                }
            }
        }
    }
}

// ---------------- MFMA sliding-window attention ----------------
// One block: one (b,h), 64-query tile. Keys [q0-128, q0+64) = 192.
// Qg/Kg: [bh][t][64] bf16; Vtg: [bh][64][2048] bf16 (dim-major). ctx: (B,T,512) bf16.
constexpr int QS = 72;    // Qs/Ks LDS row stride (shorts)
constexpr int VS = 200;   // Vt/Ps LDS row stride (shorts)

__global__ __launch_bounds__(256) void attn_mfma(const short* __restrict__ Qg,
                                                 const short* __restrict__ Kg,
                                                 const short* __restrict__ Vtg,
                                                 short* __restrict__ ctx)
{
    __shared__ short Qs[64 * QS];
    __shared__ short Ks[192 * QS];     // aliased as Ps[64*VS] later
    __shared__ short Vt[64 * VS];
    int tid = threadIdx.x;
    int w = tid >> 6, lane = tid & 63, quad = lane >> 4, l16 = lane & 15;
    int blk = blockIdx.x;
    int q0 = (blk & 31) << 6;
    int bh = blk >> 5;
    int kbase = q0 - 128;

    {
        const short* src = Qg + ((size_t)bh * 2048 + q0) * 64;
        for (int c = tid; c < 512; c += 256) {
            int row = c >> 3, off = (c & 7) * 8;
            *(short8*)(Qs + row * QS + off) = *(const short8*)(src + row * 64 + off);
        }
    }
    {
        const short* base = Kg + (size_t)bh * 2048 * 64;
        for (int c = tid; c < 1536; c += 256) {
            int row = c >> 3, off = (c & 7) * 8;
            int srow = kbase + row; srow = srow < 0 ? 0 : srow;
            *(short8*)(Ks + row * QS + off) = *(const short8*)(base + (size_t)srow * 64 + off);
        }
    }
    {
        const short* base = Vtg + (size_t)bh * 64 * 2048;
        for (int c = tid; c < 1536; c += 256) {
            int row = c / 24, cc = c - row * 24;
            int off = cc * 8;
            int scol = kbase + off; scol = scol < 0 ? 0 : scol;
            *(short8*)(Vt + row * VS + off) = *(const short8*)(base + (size_t)row * 2048 + scol);
        }
    }
    __syncthreads();

    short8 aF0 = *(const short8*)(Qs + (w * 16 + l16) * QS + quad * 8);
    short8 aF1 = *(const short8*)(Qs + (w * 16 + l16) * QS + 32 + quad * 8);
    f32x4 S[12];
    f32x4 zero = {0.f, 0.f, 0.f, 0.f};
#pragma unroll
    for (int t = 0; t < 12; ++t) S[t] = zero;
#pragma unroll
    for (int t = 0; t < 12; ++t) {
        short8 b0 = *(const short8*)(Ks + (t * 16 + l16) * QS + quad * 8);
        short8 b1 = *(const short8*)(Ks + (t * 16 + l16) * QS + 32 + quad * 8);
        S[t] = __builtin_amdgcn_mfma_f32_16x16x32_bf16(aF0, b0, S[t], 0, 0, 0);
        S[t] = __builtin_amdgcn_mfma_f32_16x16x32_bf16(aF1, b1, S[t], 0, 0, 0);
    }

    int i0 = w * 16 + quad * 4;
    float mrow[4] = {-INFINITY, -INFINITY, -INFINITY, -INFINITY};
#pragma unroll
    for (int t = 0; t < 12; ++t) {
        int jl = t * 16 + l16;
        int kg = kbase + jl;
#pragma unroll
        for (int r = 0; r < 4; ++r) {
            int dj = jl - (i0 + r);
            bool ok = (dj >= 1) && (dj <= 128) && (kg >= 0);
            float s = ok ? S[t][r] * 0.125f : -INFINITY;
            S[t][r] = s;
            mrow[r] = fmaxf(mrow[r], s);
        }
    }
#pragma unroll
    for (int off = 8; off >= 1; off >>= 1)
#pragma unroll
        for (int r = 0; r < 4; ++r)
            mrow[r] = fmaxf(mrow[r], __shfl_xor(mrow[r], off, 64));
    float sum[4] = {0.f, 0.f, 0.f, 0.f};
#pragma unroll
    for (int t = 0; t < 12; ++t)
#pragma unroll
        for (int r = 0; r < 4; ++r) {
            float p = __expf(S[t][r] - mrow[r]);
            S[t][r] = p;
            sum[r] += p;
        }
#pragma unroll
    for (int off = 8; off >= 1; off >>= 1)
#pragma unroll
        for (int r = 0; r < 4; ++r)
            sum[r] += __shfl_xor(sum[r], off, 64);
    float inv[4];
#pragma unroll
    for (int r = 0; r < 4; ++r) inv[r] = 1.0f / sum[r];

    __syncthreads();
    short* Ps = Ks;
#pragma unroll
    for (int t = 0; t < 12; ++t)
#pragma unroll
        for (int r = 0; r < 4; ++r)
            Ps[(w * 16 + quad * 4 + r) * VS + t * 16 + l16] = f2bf(S[t][r]);

    f32x4 O[4];
#pragma unroll
    for (int tN = 0; tN < 4; ++tN) O[tN] = zero;
#pragma unroll
    for (int s = 0; s < 6; ++s) {
        short8 aP = *(const short8*)(Ps + (w * 16 + l16) * VS + s * 32 + quad * 8);
#pragma unroll
        for (int tN = 0; tN < 4; ++tN) {
            short8 bV = *(const short8*)(Vt + (tN * 16 + l16) * VS + s * 32 + quad * 8);
            O[tN] = __builtin_amdgcn_mfma_f32_16x16x32_bf16(aP, bV, O[tN], 0, 0, 0);
        }
    }

    int b = bh >> 3, h = bh & 7;
#pragma unroll
    for (int tN = 0; tN < 4; ++tN)
#pragma unroll
        for (int r = 0; r < 4; ++r) {
            int trow = q0 + w * 16 + quad * 4 + r;
            ctx[((size_t)(b * 2048 + trow)) * 512 + h * 64 + tN * 16 + l16] =
                f2bf(O[tN][r] * inv[r]);
        }
}

extern "C" void kernel_launch(void* const* d_in, const int* in_sizes, int n_in,
                              void* d_out, int out_size, void* d_ws, size_t ws_size,
                              hipStream_t stream)
{
    const float* x         = (const float*)d_in[0];
    const float* in_proj_w = (const float*)d_in[1];
    const float* in_proj_b = (const float*)d_in[2];
    const float* out_w     = (const float*)d_in[3];
    const float* out_b     = (const float*)d_in[4];
    const float* ln1_g     = (const float*)d_in[5];
    const float* ln1_b     = (const float*)d_in[6];
    const float* ln2_g     = (const float*)d_in[7];
    const float* ln2_b     = (const float*)d_in[8];
    const float* w1        = (const float*)d_in[9];
    const float* b1        = (const float*)d_in[10];
    const float* w2        = (const float*)d_in[11];
    const float* b2        = (const float*)d_in[12];
    float* out = (float*)d_out;

    char* ws = (char*)d_ws;
    short* attnQ = (short*)ws;
    short* attnK = (short*)(ws + (size_t)8 * 1024 * 1024);
    short* attnV = (short*)(ws + (size_t)16 * 1024 * 1024);
    short* hbuf  = (short*)ws;                                  // overlays attnQKV
    short* regB  = (short*)(ws + (size_t)32 * 1024 * 1024);
    short* wq  = (short*)(ws + (size_t)40 * 1024 * 1024);
    short* wo  = wq + (size_t)QKVD * Dn;
    short* w1b = wo + (size_t)Dn * Dn;
    short* w2b = w1b + (size_t)Fn * Dn;

    cvt_bf16<<<(QKVD * Dn / 4 + 255) / 256, 256, 0, stream>>>(in_proj_w, wq, QKVD * Dn / 4);
    cvt_bf16<<<(Dn * Dn / 4 + 255) / 256, 256, 0, stream>>>(out_w, wo, Dn * Dn / 4);
    cvt_bf16<<<(Fn * Dn / 4 + 255) / 256, 256, 0, stream>>>(w1, w1b, Fn * Dn / 4);
    cvt_bf16<<<(Dn * Fn / 4 + 255) / 256, 256, 0, stream>>>(w2, w2b, Dn * Fn / 4);

    // 1) x2 = LN1(x) -> bf16
    ln_kernel<<<Mrows, 64, 0, stream>>>(x, ln1_g, ln1_b, regB);
    // 2) qkv = x2 @ in_proj_w^T + b -> bf16 attention layouts
    gemm_mfma<3><<<dim3(QKVD / 128, Mrows / 128), 256, 0, stream>>>(
        regB, wq, in_proj_b, nullptr, nullptr, attnQ, attnK, attnV, Mrows, QKVD, Dn);
    // 3) ctx = attention -> bf16 (B,T,512)
    attn_mfma<<<Bn * Hn * (Tn / 64), 256, 0, stream>>>(attnQ, attnK, attnV, regB);
    // 4) out = x + ctx @ out_w^T + out_b -> f32
    gemm_mfma<1><<<dim3(Dn / 128, Mrows / 128), 256, 0, stream>>>(
        regB, wo, out_b, x, out, nullptr, nullptr, nullptr, Mrows, Dn, Dn);
    // 5) x3 = LN2(out) -> bf16
    ln_kernel<<<Mrows, 64, 0, stream>>>(out, ln2_g, ln2_b, regB);
    // 6) h = gelu(x3 @ w1^T + b1) -> bf16 (overlays dead attn buffers)
    gemm_mfma<2><<<dim3(Fn / 128, Mrows / 128), 256, 0, stream>>>(
        regB, w1b, b1, nullptr, hbuf, nullptr, nullptr, nullptr, Mrows, Fn, Dn);
    // 7) out = out + h @ w2^T + b2 -> f32
    gemm_mfma<1><<<dim3(Dn / 128, Mrows / 128), 256, 0, stream>>>(
        hbuf, w2b, b2, out, out, nullptr, nullptr, nullptr, Mrows, Dn, Fn);
}

// Round 5
// 234.530 us; speedup vs baseline: 5.2569x; 1.1098x over previous
//
#include <hip/hip_runtime.h>
#include <math.h>

// Problem constants
constexpr int Bn = 4;
constexpr int Tn = 2048;
constexpr int Dn = 512;
constexpr int Hn = 8;
constexpr int HDn = 64;       // head dim
constexpr int Fn = 2048;
constexpr int WIN = 128;
constexpr float EPS = 1e-5f;
constexpr int Mrows = Bn * Tn;          // 8192
constexpr int QKVD = 3 * Dn;            // 1536

using short8 = __attribute__((ext_vector_type(8))) short;
using f32x4  = __attribute__((ext_vector_type(4))) float;

// fp32 -> bf16 (RNE) as raw short
__device__ __forceinline__ short f2bf(float f) {
    unsigned u = __float_as_uint(f);
    unsigned r = (u + 0x7FFFu + ((u >> 16) & 1u)) >> 16;
    return (short)r;
}

__device__ __forceinline__ float gelu_exact(float v) {
    return 0.5f * v * (1.0f + erff(v * 0.70710678118654752f));
}

// async 16B global -> LDS (wave-uniform LDS base; HW scatters lane i at base+16*i)
__device__ __forceinline__ void async16(const short* g, short* l) {
    __builtin_amdgcn_global_load_lds(
        (const __attribute__((address_space(1))) void*)g,
        (__attribute__((address_space(3))) void*)l,
        16, 0, 0);
}

// ---------------- fp32 -> bf16 convert (weights) ----------------
__global__ __launch_bounds__(256) void cvt_bf16(const float* __restrict__ src,
                                                short* __restrict__ dst, int n4)
{
    int i = blockIdx.x * 256 + threadIdx.x;
    if (i < n4) {
        float4 v = ((const float4*)src)[i];
        short4 o;
        o.x = f2bf(v.x); o.y = f2bf(v.y); o.z = f2bf(v.z); o.w = f2bf(v.w);
        ((short4*)dst)[i] = o;
    }
}

// ---------------- LayerNorm: one wave per row of 512; bf16 output ----------------
__global__ __launch_bounds__(64) void ln_kernel(const float* __restrict__ x,
                                                const float* __restrict__ g,
                                                const float* __restrict__ b,
                                                short* __restrict__ y)
{
    int row = blockIdx.x;
    int lane = threadIdx.x;
    const float4* xr = (const float4*)(x + (size_t)row * Dn);
    float4 v0 = xr[lane];
    float4 v1 = xr[lane + 64];
    float s = v0.x + v0.y + v0.z + v0.w + v1.x + v1.y + v1.z + v1.w;
#pragma unroll
    for (int off = 32; off >= 1; off >>= 1) s += __shfl_xor(s, off, 64);
    float mu = s * (1.0f / Dn);
    float d0x = v0.x - mu, d0y = v0.y - mu, d0z = v0.z - mu, d0w = v0.w - mu;
    float d1x = v1.x - mu, d1y = v1.y - mu, d1z = v1.z - mu, d1w = v1.w - mu;
    float q = d0x*d0x + d0y*d0y + d0z*d0z + d0w*d0w
            + d1x*d1x + d1y*d1y + d1z*d1z + d1w*d1w;
#pragma unroll
    for (int off = 32; off >= 1; off >>= 1) q += __shfl_xor(q, off, 64);
    float inv = rsqrtf(q * (1.0f / Dn) + EPS);
    const float4* gr = (const float4*)g;
    const float4* br = (const float4*)b;
    float4 g0 = gr[lane], g1 = gr[lane + 64];
    float4 b0 = br[lane], b1 = br[lane + 64];
    short4 a0, a1;
    a0.x = f2bf(d0x * inv * g0.x + b0.x);
    a0.y = f2bf(d0y * inv * g0.y + b0.y);
    a0.z = f2bf(d0z * inv * g0.z + b0.z);
    a0.w = f2bf(d0w * inv * g0.w + b0.w);
    a1.x = f2bf(d1x * inv * g1.x + b1.x);
    a1.y = f2bf(d1y * inv * g1.y + b1.y);
    a1.z = f2bf(d1z * inv * g1.z + b1.z);
    a1.w = f2bf(d1w * inv * g1.w + b1.w);
    short4* yr = (short4*)(y + (size_t)row * Dn);
    yr[lane] = a0;
    yr[lane + 64] = a1;
}

// ---------------- bf16 MFMA GEMM (NT), double-buffered, swizzled LDS ----------------
// C[m,n] = sum_k A[m,k]*Bw[n,k] + bias[n]
// MODE 1: f32 out + bias + resid (direct stores, full 64B lines).
// MODE 2: bf16 out, gelu -> LDS repack -> short8 stores (full-line writes).
// MODE 3: bf16 out into attention layouts via LDS repack (q/k row-major, v transposed).
// Tile 128x128, 4 waves (2x2), each wave 64x64 via 4x4 mfma_16x16x32 frags.
// LDS swizzle: chunk ^= (row*BK>>6)&(NCH-1)  -> 2-way-max bank aliasing (free).
template <int MODE, int BK>
__global__ __launch_bounds__(256) void gemm_mfma(const short* __restrict__ A,
                                                 const short* __restrict__ Bw,
                                                 const float* __restrict__ bias,
                                                 const float* __restrict__ resid,
                                                 void* __restrict__ Cout,
                                                 short* __restrict__ q_out,
                                                 short* __restrict__ k_out,
                                                 short* __restrict__ v_out,
                                                 int M, int N, int K)
{
    constexpr int NCH = BK / 8;                 // 16B chunks per row
    constexpr int LGN = (BK == 32) ? 2 : 3;
    constexpr int RPI = 512 / BK;               // rows covered per staging instr
    constexpr int NI  = 32 / RPI;               // staging instrs per wave per matrix
    constexpr int BUF = 128 * BK;               // shorts per buffer per matrix
    constexpr int KK  = BK / 32;                // mfma k-steps per tile
    constexpr int SMSZ = (4 * BUF > 17408) ? 4 * BUF : 17408;
    __shared__ short SMEM[SMSZ];
    short* Asb = SMEM;                          // [2][BUF]
    short* Bsb = SMEM + 2 * BUF;                // [2][BUF]

    int tid = threadIdx.x;
    int w = tid >> 6, lane = tid & 63;
    int wr = w >> 1, wc = w & 1;
    int m0 = blockIdx.y * 128, n0 = blockIdx.x * 128;
    int quad = lane >> 4, l16 = lane & 15;

    f32x4 zero = {0.f, 0.f, 0.f, 0.f};
    f32x4 acc[4][4];
#pragma unroll
    for (int i = 0; i < 4; ++i)
#pragma unroll
        for (int j = 0; j < 4; ++j) acc[i][j] = zero;

    // staging source pointers (swizzled global chunk per lane)
    int rl = lane >> LGN;                       // row within instr
    int ch = lane & (NCH - 1);                  // chunk within row
    const short* Ag[NI];
    const short* Bg[NI];
    int ldsOff[NI];
#pragma unroll
    for (int s = 0; s < NI; ++s) {
        int rowl = w * 32 + s * RPI + rl;
        int csw = (ch ^ ((rowl * BK >> 6) & (NCH - 1))) * 8;
        Ag[s] = A + (size_t)(m0 + rowl) * K + csw;
        Bg[s] = Bw + (size_t)(n0 + rowl) * K + csw;
        ldsOff[s] = (w * 32 + s * RPI) * BK;
    }

    auto stage = [&](int kt, int pp) {
#pragma unroll
        for (int s = 0; s < NI; ++s) {
            async16(Ag[s] + kt, Asb + pp * BUF + ldsOff[s]);
            async16(Bg[s] + kt, Bsb + pp * BUF + ldsOff[s]);
        }
    };

    stage(0, 0);
    int p = 0;
    for (int kt = 0; kt < K; kt += BK) {
        __syncthreads();                        // buf[p] staged; prior reads done
        if (kt + BK < K) stage(kt + BK, p ^ 1); // prefetch overlaps MFMA below
        short8 aF[KK][4], bF[KK][4];
#pragma unroll
        for (int kk = 0; kk < KK; ++kk)
#pragma unroll
            for (int i = 0; i < 4; ++i) {
                int ra = wr * 64 + i * 16 + l16;
                int rb = wc * 64 + i * 16 + l16;
                int cs = ((kk * 4 + quad) ^ ((ra * BK >> 6) & (NCH - 1))) * 8;
                aF[kk][i] = *(const short8*)(Asb + p * BUF + ra * BK + cs);
                bF[kk][i] = *(const short8*)(Bsb + p * BUF + rb * BK + cs);
            }
#pragma unroll
        for (int kk = 0; kk < KK; ++kk)
#pragma unroll
            for (int i = 0; i < 4; ++i)
#pragma unroll
                for (int j = 0; j < 4; ++j)
                    acc[i][j] = __builtin_amdgcn_mfma_f32_16x16x32_bf16(
                        aF[kk][i], bF[kk][j], acc[i][j], 0, 0, 0);
        p ^= 1;
    }

    if constexpr (MODE == 3) {
        __syncthreads();                        // K-loop LDS dead -> alias as repack
        short* rp = SMEM + w * 4352;            // 64 x 68
        int b = m0 >> 11;
        int ncol0 = n0 + wc * 64;
        int sec = ncol0 >> 9;                   // 0=q 1=k 2=v
        int h = (ncol0 & 511) >> 6;
        int bh = b * 8 + h;
        int t0 = (m0 & 2047) + wr * 64;
        if (sec == 2) {
            // transposed into rp: rp[d*68 + t_local]
#pragma unroll
            for (int j = 0; j < 4; ++j) {
                int d = j * 16 + l16;
                float bv = bias[ncol0 + j * 16 + l16];
#pragma unroll
                for (int i = 0; i < 4; ++i)
#pragma unroll
                    for (int r = 0; r < 4; ++r)
                        rp[d * 68 + i * 16 + quad * 4 + r] = f2bf(acc[i][j][r] + bv);
            }
#pragma unroll
            for (int it = 0; it < 8; ++it) {
                int row = it * 8 + (lane >> 3);        // d
                int off = (lane & 7) * 8;              // t chunk
                *(short8*)(v_out + ((size_t)bh * 64 + row) * 2048 + t0 + off) =
                    *(const short8*)(rp + row * 68 + off);
            }
        } else {
            short* dst = (sec == 0 ? q_out : k_out);
#pragma unroll
            for (int j = 0; j < 4; ++j) {
                int d = j * 16 + l16;
                float bv = bias[ncol0 + j * 16 + l16];
#pragma unroll
                for (int i = 0; i < 4; ++i)
#pragma unroll
                    for (int r = 0; r < 4; ++r)
                        rp[(i * 16 + quad * 4 + r) * 68 + d] = f2bf(acc[i][j][r] + bv);
            }
#pragma unroll
            for (int it = 0; it < 8; ++it) {
                int row = it * 8 + (lane >> 3);        // t_local
                int off = (lane & 7) * 8;              // d chunk
                *(short8*)(dst + ((size_t)bh * 2048 + t0 + row) * 64 + off) =
                    *(const short8*)(rp + row * 68 + off);
            }
        }
        return;
    }

    if constexpr (MODE == 2) {
        __syncthreads();                        // K-loop LDS dead -> alias as repack
        short* rp = SMEM + w * 4352;            // 64 x 68
        short* Cb = (short*)Cout;
#pragma unroll
        for (int j = 0; j < 4; ++j) {
            float bv = bias[n0 + wc * 64 + j * 16 + l16];
#pragma unroll
            for (int i = 0; i < 4; ++i)
#pragma unroll
                for (int r = 0; r < 4; ++r)
                    rp[(i * 16 + quad * 4 + r) * 68 + j * 16 + l16] =
                        f2bf(gelu_exact(acc[i][j][r] + bv));
        }
#pragma unroll
        for (int it = 0; it < 8; ++it) {
            int row = it * 8 + (lane >> 3);            // m local
            int off = (lane & 7) * 8;                  // n chunk
            *(short8*)(Cb + (size_t)(m0 + wr * 64 + row) * N + n0 + wc * 64 + off) =
                *(const short8*)(rp + row * 68 + off);
        }
        return;
    }

    // MODE 1: f32 + bias + resid, direct stores (full 64B lines per quad)
    float* Cf = (float*)Cout;
#pragma unroll
    for (int j = 0; j < 4; ++j) {
        int n = n0 + wc * 64 + j * 16 + l16;
        float bv = bias[n];
#pragma unroll
        for (int i = 0; i < 4; ++i) {
            int mbase = m0 + wr * 64 + i * 16 + quad * 4;
#pragma unroll
            for (int r = 0; r < 4; ++r) {
                size_t idx = (size_t)(mbase + r) * N + n;
                Cf[idx] = acc[i][j][r] + bv + resid[idx];
            }
        }
    }
}

// ---------------- MFMA sliding-window attention ----------------
// One block: one (b,h), 64-query tile. Keys [q0-128, q0+64) = 192.
// Qg/Kg: [bh][t][64] bf16; Vtg: [bh][64][2048] bf16 (dim-major). ctx: (B,T,512) bf16.
constexpr int QS = 72;    // Qs/Ks LDS row stride (shorts)
constexpr int VS = 200;   // Vt/Ps LDS row stride (shorts)

__global__ __launch_bounds__(256) void attn_mfma(const short* __restrict__ Qg,
                                                 const short* __restrict__ Kg,
                                                 const short* __restrict__ Vtg,
                                                 short* __restrict__ ctx)
{
    __shared__ short Qs[64 * QS];
    __shared__ short Ks[192 * QS];     // aliased as Ps[64*VS] later
    __shared__ short Vt[64 * VS];
    int tid = threadIdx.x;
    int w = tid >> 6, lane = tid & 63, quad = lane >> 4, l16 = lane & 15;
    int blk = blockIdx.x;
    int q0 = (blk & 31) << 6;
    int bh = blk >> 5;
    int kbase = q0 - 128;

    {
        const short* src = Qg + ((size_t)bh * 2048 + q0) * 64;
        for (int c = tid; c < 512; c += 256) {
            int row = c >> 3, off = (c & 7) * 8;
            *(short8*)(Qs + row * QS + off) = *(const short8*)(src + row * 64 + off);
        }
    }
    {
        const short* base = Kg + (size_t)bh * 2048 * 64;
        for (int c = tid; c < 1536; c += 256) {
            int row = c >> 3, off = (c & 7) * 8;
            int srow = kbase + row; srow = srow < 0 ? 0 : srow;
            *(short8*)(Ks + row * QS + off) = *(const short8*)(base + (size_t)srow * 64 + off);
        }
    }
    {
        const short* base = Vtg + (size_t)bh * 64 * 2048;
        for (int c = tid; c < 1536; c += 256) {
            int row = c / 24, cc = c - row * 24;
            int off = cc * 8;
            int scol = kbase + off; scol = scol < 0 ? 0 : scol;
            *(short8*)(Vt + row * VS + off) = *(const short8*)(base + (size_t)row * 2048 + scol);
        }
    }
    __syncthreads();

    short8 aF0 = *(const short8*)(Qs + (w * 16 + l16) * QS + quad * 8);
    short8 aF1 = *(const short8*)(Qs + (w * 16 + l16) * QS + 32 + quad * 8);
    f32x4 S[12];
    f32x4 zero = {0.f, 0.f, 0.f, 0.f};
#pragma unroll
    for (int t = 0; t < 12; ++t) S[t] = zero;
#pragma unroll
    for (int t = 0; t < 12; ++t) {
        short8 b0 = *(const short8*)(Ks + (t * 16 + l16) * QS + quad * 8);
        short8 b1 = *(const short8*)(Ks + (t * 16 + l16) * QS + 32 + quad * 8);
        S[t] = __builtin_amdgcn_mfma_f32_16x16x32_bf16(aF0, b0, S[t], 0, 0, 0);
        S[t] = __builtin_amdgcn_mfma_f32_16x16x32_bf16(aF1, b1, S[t], 0, 0, 0);
    }

    int i0 = w * 16 + quad * 4;
    float mrow[4] = {-INFINITY, -INFINITY, -INFINITY, -INFINITY};
#pragma unroll
    for (int t = 0; t < 12; ++t) {
        int jl = t * 16 + l16;
        int kg = kbase + jl;
#pragma unroll
        for (int r = 0; r < 4; ++r) {
            int dj = jl - (i0 + r);
            bool ok = (dj >= 1) && (dj <= 128) && (kg >= 0);
            float s = ok ? S[t][r] * 0.125f : -INFINITY;
            S[t][r] = s;
            mrow[r] = fmaxf(mrow[r], s);
        }
    }
#pragma unroll
    for (int off = 8; off >= 1; off >>= 1)
#pragma unroll
        for (int r = 0; r < 4; ++r)
            mrow[r] = fmaxf(mrow[r], __shfl_xor(mrow[r], off, 64));
    float sum[4] = {0.f, 0.f, 0.f, 0.f};
#pragma unroll
    for (int t = 0; t < 12; ++t)
#pragma unroll
        for (int r = 0; r < 4; ++r) {
            float p = __expf(S[t][r] - mrow[r]);
            S[t][r] = p;
            sum[r] += p;
        }
#pragma unroll
    for (int off = 8; off >= 1; off >>= 1)
#pragma unroll
        for (int r = 0; r < 4; ++r)
            sum[r] += __shfl_xor(sum[r], off, 64);
    float inv[4];
#pragma unroll
    for (int r = 0; r < 4; ++r) inv[r] = 1.0f / sum[r];

    __syncthreads();
    short* Ps = Ks;
#pragma unroll
    for (int t = 0; t < 12; ++t)
#pragma unroll
        for (int r = 0; r < 4; ++r)
            Ps[(w * 16 + quad * 4 + r) * VS + t * 16 + l16] = f2bf(S[t][r]);

    f32x4 O[4];
#pragma unroll
    for (int tN = 0; tN < 4; ++tN) O[tN] = zero;
#pragma unroll
    for (int s = 0; s < 6; ++s) {
        short8 aP = *(const short8*)(Ps + (w * 16 + l16) * VS + s * 32 + quad * 8);
#pragma unroll
        for (int tN = 0; tN < 4; ++tN) {
            short8 bV = *(const short8*)(Vt + (tN * 16 + l16) * VS + s * 32 + quad * 8);
            O[tN] = __builtin_amdgcn_mfma_f32_16x16x32_bf16(aP, bV, O[tN], 0, 0, 0);
        }
    }

    int b = bh >> 3, h = bh & 7;
#pragma unroll
    for (int tN = 0; tN < 4; ++tN)
#pragma unroll
        for (int r = 0; r < 4; ++r) {
            int trow = q0 + w * 16 + quad * 4 + r;
            ctx[((size_t)(b * 2048 + trow)) * 512 + h * 64 + tN * 16 + l16] =
                f2bf(O[tN][r] * inv[r]);
        }
}

extern "C" void kernel_launch(void* const* d_in, const int* in_sizes, int n_in,
                              void* d_out, int out_size, void* d_ws, size_t ws_size,
                              hipStream_t stream)
{
    const float* x         = (const float*)d_in[0];
    const float* in_proj_w = (const float*)d_in[1];
    const float* in_proj_b = (const float*)d_in[2];
    const float* out_w     = (const float*)d_in[3];
    const float* out_b     = (const float*)d_in[4];
    const float* ln1_g     = (const float*)d_in[5];
    const float* ln1_b     = (const float*)d_in[6];
    const float* ln2_g     = (const float*)d_in[7];
    const float* ln2_b     = (const float*)d_in[8];
    const float* w1        = (const float*)d_in[9];
    const float* b1        = (const float*)d_in[10];
    const float* w2        = (const float*)d_in[11];
    const float* b2        = (const float*)d_in[12];
    float* out = (float*)d_out;

    char* ws = (char*)d_ws;
    short* attnQ = (short*)ws;
    short* attnK = (short*)(ws + (size_t)8 * 1024 * 1024);
    short* attnV = (short*)(ws + (size_t)16 * 1024 * 1024);
    short* hbuf  = (short*)ws;                                  // overlays attnQKV
    short* regB  = (short*)(ws + (size_t)32 * 1024 * 1024);
    short* wq  = (short*)(ws + (size_t)40 * 1024 * 1024);
    short* wo  = wq + (size_t)QKVD * Dn;
    short* w1b = wo + (size_t)Dn * Dn;
    short* w2b = w1b + (size_t)Fn * Dn;

    cvt_bf16<<<(QKVD * Dn / 4 + 255) / 256, 256, 0, stream>>>(in_proj_w, wq, QKVD * Dn / 4);
    cvt_bf16<<<(Dn * Dn / 4 + 255) / 256, 256, 0, stream>>>(out_w, wo, Dn * Dn / 4);
    cvt_bf16<<<(Fn * Dn / 4 + 255) / 256, 256, 0, stream>>>(w1, w1b, Fn * Dn / 4);
    cvt_bf16<<<(Dn * Fn / 4 + 255) / 256, 256, 0, stream>>>(w2, w2b, Dn * Fn / 4);

    // 1) x2 = LN1(x) -> bf16
    ln_kernel<<<Mrows, 64, 0, stream>>>(x, ln1_g, ln1_b, regB);
    // 2) qkv = x2 @ in_proj_w^T + b -> bf16 attention layouts
    gemm_mfma<3, 32><<<dim3(QKVD / 128, Mrows / 128), 256, 0, stream>>>(
        regB, wq, in_proj_b, nullptr, nullptr, attnQ, attnK, attnV, Mrows, QKVD, Dn);
    // 3) ctx = attention -> bf16 (B,T,512)
    attn_mfma<<<Bn * Hn * (Tn / 64), 256, 0, stream>>>(attnQ, attnK, attnV, regB);
    // 4) out = x + ctx @ out_w^T + out_b -> f32
    gemm_mfma<1, 64><<<dim3(Dn / 128, Mrows / 128), 256, 0, stream>>>(
        regB, wo, out_b, x, out, nullptr, nullptr, nullptr, Mrows, Dn, Dn);
    // 5) x3 = LN2(out) -> bf16
    ln_kernel<<<Mrows, 64, 0, stream>>>(out, ln2_g, ln2_b, regB);
    // 6) h = gelu(x3 @ w1^T + b1) -> bf16 (overlays dead attn buffers)
    gemm_mfma<2, 32><<<dim3(Fn / 128, Mrows / 128), 256, 0, stream>>>(
        regB, w1b, b1, nullptr, hbuf, nullptr, nullptr, nullptr, Mrows, Fn, Dn);
    // 7) out = out + h @ w2^T + b2 -> f32
    gemm_mfma<1, 64><<<dim3(Dn / 128, Mrows / 128), 256, 0, stream>>>(
        hbuf, w2b, b2, out, out, nullptr, nullptr, nullptr, Mrows, Dn, Fn);
}

// Round 6
// 223.309 us; speedup vs baseline: 5.5211x; 1.0502x over previous
//
#include <hip/hip_runtime.h>
#include <math.h>

// Problem constants
constexpr int Bn = 4;
constexpr int Tn = 2048;
constexpr int Dn = 512;
constexpr int Hn = 8;
constexpr int HDn = 64;       // head dim
constexpr int Fn = 2048;
constexpr int WIN = 128;
constexpr float EPS = 1e-5f;
constexpr int Mrows = Bn * Tn;          // 8192
constexpr int QKVD = 3 * Dn;            // 1536

using short8 = __attribute__((ext_vector_type(8))) short;
using f32x4  = __attribute__((ext_vector_type(4))) float;

// fp32 -> bf16 (RNE) as raw short
__device__ __forceinline__ short f2bf(float f) {
    unsigned u = __float_as_uint(f);
    unsigned r = (u + 0x7FFFu + ((u >> 16) & 1u)) >> 16;
    return (short)r;
}

__device__ __forceinline__ float gelu_exact(float v) {
    return 0.5f * v * (1.0f + erff(v * 0.70710678118654752f));
}

// async 16B global -> LDS (wave-uniform LDS base; HW scatters lane i at base+16*i)
__device__ __forceinline__ void async16(const short* g, short* l) {
    __builtin_amdgcn_global_load_lds(
        (const __attribute__((address_space(1))) void*)g,
        (__attribute__((address_space(3))) void*)l,
        16, 0, 0);
}

// ---------------- fp32 -> bf16 convert, all 4 weights in one launch ----------------
// sizes (float4 units): wq 196608 | wo 65536 | w1 262144 | w2 262144  -> 786432 total
__global__ __launch_bounds__(256) void cvt_all(const float* __restrict__ s0,
                                               const float* __restrict__ s1,
                                               const float* __restrict__ s2,
                                               const float* __restrict__ s3,
                                               short* __restrict__ d0,
                                               short* __restrict__ d1,
                                               short* __restrict__ d2,
                                               short* __restrict__ d3)
{
    int i = blockIdx.x * 256 + threadIdx.x;
    const float* src; short* dst; int j;
    if (i < 196608)      { src = s0; dst = d0; j = i; }
    else if (i < 262144) { src = s1; dst = d1; j = i - 196608; }
    else if (i < 524288) { src = s2; dst = d2; j = i - 262144; }
    else                 { src = s3; dst = d3; j = i - 524288; }
    float4 v = ((const float4*)src)[j];
    short4 o;
    o.x = f2bf(v.x); o.y = f2bf(v.y); o.z = f2bf(v.z); o.w = f2bf(v.w);
    ((short4*)dst)[j] = o;
}

// ---------------- LayerNorm: one wave per row of 512; bf16 output ----------------
__global__ __launch_bounds__(64) void ln_kernel(const float* __restrict__ x,
                                                const float* __restrict__ g,
                                                const float* __restrict__ b,
                                                short* __restrict__ y)
{
    int row = blockIdx.x;
    int lane = threadIdx.x;
    const float4* xr = (const float4*)(x + (size_t)row * Dn);
    float4 v0 = xr[lane];
    float4 v1 = xr[lane + 64];
    float s = v0.x + v0.y + v0.z + v0.w + v1.x + v1.y + v1.z + v1.w;
#pragma unroll
    for (int off = 32; off >= 1; off >>= 1) s += __shfl_xor(s, off, 64);
    float mu = s * (1.0f / Dn);
    float d0x = v0.x - mu, d0y = v0.y - mu, d0z = v0.z - mu, d0w = v0.w - mu;
    float d1x = v1.x - mu, d1y = v1.y - mu, d1z = v1.z - mu, d1w = v1.w - mu;
    float q = d0x*d0x + d0y*d0y + d0z*d0z + d0w*d0w
            + d1x*d1x + d1y*d1y + d1z*d1z + d1w*d1w;
#pragma unroll
    for (int off = 32; off >= 1; off >>= 1) q += __shfl_xor(q, off, 64);
    float inv = rsqrtf(q * (1.0f / Dn) + EPS);
    const float4* gr = (const float4*)g;
    const float4* br = (const float4*)b;
    float4 g0 = gr[lane], g1 = gr[lane + 64];
    float4 b0 = br[lane], b1 = br[lane + 64];
    short4 a0, a1;
    a0.x = f2bf(d0x * inv * g0.x + b0.x);
    a0.y = f2bf(d0y * inv * g0.y + b0.y);
    a0.z = f2bf(d0z * inv * g0.z + b0.z);
    a0.w = f2bf(d0w * inv * g0.w + b0.w);
    a1.x = f2bf(d1x * inv * g1.x + b1.x);
    a1.y = f2bf(d1y * inv * g1.y + b1.y);
    a1.z = f2bf(d1z * inv * g1.z + b1.z);
    a1.w = f2bf(d1w * inv * g1.w + b1.w);
    short4* yr = (short4*)(y + (size_t)row * Dn);
    yr[lane] = a0;
    yr[lane + 64] = a1;
}

// ---------------- bf16 MFMA GEMM (NT), double-buffered, swizzled LDS ----------------
// C[m,n] = sum_k A[m,k]*Bw[n,k] + bias[n]
// MODE 1: f32 out + bias + resid (direct stores).
// MODE 2: bf16 out, gelu -> two-phase LDS repack -> short8 stores.
// MODE 3: bf16 out into attention layouts via two-phase LDS repack.
// Tile 128x128, 4 waves (2x2). 1D grid with XCD-aware swizzle (bid&7 = XCD;
// each XCD owns m-strips x, x+8, ... across all n-tiles -> A-strip L2 reuse).
// LDS swizzle: chunk ^= (row*BK>>6)&(NCH-1)  -> 2-way-max bank aliasing (free).
template <int MODE, int BK>
__global__ __launch_bounds__(256) void gemm_mfma(const short* __restrict__ A,
                                                 const short* __restrict__ Bw,
                                                 const float* __restrict__ bias,
                                                 const float* __restrict__ resid,
                                                 void* __restrict__ Cout,
                                                 short* __restrict__ q_out,
                                                 short* __restrict__ k_out,
                                                 short* __restrict__ v_out,
                                                 int M, int N, int K)
{
    constexpr int NCH = BK / 8;                 // 16B chunks per row
    constexpr int LGN = (BK == 32) ? 2 : 3;
    constexpr int RPI = 512 / BK;               // rows covered per staging instr
    constexpr int NI  = 32 / RPI;               // staging instrs per wave per matrix
    constexpr int BUF = 128 * BK;               // shorts per buffer per matrix
    constexpr int KK  = BK / 32;                // mfma k-steps per tile
    __shared__ short SMEM[4 * BUF];             // also hosts repack (8704 <= 16384)
    short* Asb = SMEM;                          // [2][BUF]
    short* Bsb = SMEM + 2 * BUF;                // [2][BUF]

    int tid = threadIdx.x;
    int w = tid >> 6, lane = tid & 63;
    int wr = w >> 1, wc = w & 1;
    // XCD-aware swizzle (mT = M/128 assumed %8==0)
    int nN = N >> 7;
    int bid = blockIdx.x;
    int xcd = bid & 7, sq = bid >> 3;
    int mi = xcd + 8 * (sq / nN);
    int ni = sq % nN;
    int m0 = mi * 128, n0 = ni * 128;
    int quad = lane >> 4, l16 = lane & 15;

    f32x4 zero = {0.f, 0.f, 0.f, 0.f};
    f32x4 acc[4][4];
#pragma unroll
    for (int i = 0; i < 4; ++i)
#pragma unroll
        for (int j = 0; j < 4; ++j) acc[i][j] = zero;

    int rl = lane >> LGN;                       // row within instr
    int ch = lane & (NCH - 1);                  // chunk within row
    const short* Ag[NI];
    const short* Bg[NI];
    int ldsOff[NI];
#pragma unroll
    for (int s = 0; s < NI; ++s) {
        int rowl = w * 32 + s * RPI + rl;
        int csw = (ch ^ ((rowl * BK >> 6) & (NCH - 1))) * 8;
        Ag[s] = A + (size_t)(m0 + rowl) * K + csw;
        Bg[s] = Bw + (size_t)(n0 + rowl) * K + csw;
        ldsOff[s] = (w * 32 + s * RPI) * BK;
    }

    auto stage = [&](int kt, int pp) {
#pragma unroll
        for (int s = 0; s < NI; ++s) {
            async16(Ag[s] + kt, Asb + pp * BUF + ldsOff[s]);
            async16(Bg[s] + kt, Bsb + pp * BUF + ldsOff[s]);
        }
    };

    stage(0, 0);
    int p = 0;
    for (int kt = 0; kt < K; kt += BK) {
        __syncthreads();                        // buf[p] staged; prior reads done
        if (kt + BK < K) stage(kt + BK, p ^ 1); // prefetch overlaps MFMA below
        short8 aF[KK][4], bF[KK][4];
#pragma unroll
        for (int kk = 0; kk < KK; ++kk)
#pragma unroll
            for (int i = 0; i < 4; ++i) {
                int ra = wr * 64 + i * 16 + l16;
                int rb = wc * 64 + i * 16 + l16;
                int cs = ((kk * 4 + quad) ^ ((ra * BK >> 6) & (NCH - 1))) * 8;
                aF[kk][i] = *(const short8*)(Asb + p * BUF + ra * BK + cs);
                bF[kk][i] = *(const short8*)(Bsb + p * BUF + rb * BK + cs);
            }
#pragma unroll
        for (int kk = 0; kk < KK; ++kk)
#pragma unroll
            for (int i = 0; i < 4; ++i)
#pragma unroll
                for (int j = 0; j < 4; ++j)
                    acc[i][j] = __builtin_amdgcn_mfma_f32_16x16x32_bf16(
                        aF[kk][i], bF[kk][j], acc[i][j], 0, 0, 0);
        p ^= 1;
    }

    if constexpr (MODE == 3) {
        __syncthreads();                        // K-loop LDS dead -> alias as repack
        short* rp = SMEM + w * 2176;            // 32 x 68 per phase
        int b = m0 >> 11;
        int ncol0 = n0 + wc * 64;
        int sec = ncol0 >> 9;                   // 0=q 1=k 2=v
        int h = (ncol0 & 511) >> 6;
        int bh = b * 8 + h;
        int t0 = (m0 & 2047) + wr * 64;
        if (sec == 2) {
            // transpose: phase h covers d in [32h, 32h+32)
#pragma unroll
            for (int ph = 0; ph < 2; ++ph) {
#pragma unroll
                for (int j = 2 * ph; j < 2 * ph + 2; ++j) {
                    int dl = (j - 2 * ph) * 16 + l16;
                    float bv = bias[ncol0 + j * 16 + l16];
#pragma unroll
                    for (int i = 0; i < 4; ++i)
#pragma unroll
                        for (int r = 0; r < 4; ++r)
                            rp[dl * 68 + i * 16 + quad * 4 + r] = f2bf(acc[i][j][r] + bv);
                }
#pragma unroll
                for (int it = 0; it < 4; ++it) {
                    int row = it * 8 + (lane >> 3);        // d local
                    int off = (lane & 7) * 8;              // t chunk
                    *(short8*)(v_out + ((size_t)bh * 64 + 32 * ph + row) * 2048 + t0 + off) =
                        *(const short8*)(rp + row * 68 + off);
                }
            }
        } else {
            short* dst = (sec == 0 ? q_out : k_out);
#pragma unroll
            for (int ph = 0; ph < 2; ++ph) {
#pragma unroll
                for (int i = 2 * ph; i < 2 * ph + 2; ++i) {
                    int tl = (i - 2 * ph) * 16 + quad * 4;
#pragma unroll
                    for (int j = 0; j < 4; ++j) {
                        float bv = bias[ncol0 + j * 16 + l16];
#pragma unroll
                        for (int r = 0; r < 4; ++r)
                            rp[(tl + r) * 68 + j * 16 + l16] = f2bf(acc[i][j][r] + bv);
                    }
                }
#pragma unroll
                for (int it = 0; it < 4; ++it) {
                    int row = it * 8 + (lane >> 3);        // t local
                    int off = (lane & 7) * 8;              // d chunk
                    *(short8*)(dst + ((size_t)bh * 2048 + t0 + 32 * ph + row) * 64 + off) =
                        *(const short8*)(rp + row * 68 + off);
                }
            }
        }
        return;
    }

    if constexpr (MODE == 2) {
        __syncthreads();                        // K-loop LDS dead -> alias as repack
        short* rp = SMEM + w * 2176;            // 32 x 68 per phase
        short* Cb = (short*)Cout;
#pragma unroll
        for (int ph = 0; ph < 2; ++ph) {
#pragma unroll
            for (int i = 2 * ph; i < 2 * ph + 2; ++i) {
                int ml = (i - 2 * ph) * 16 + quad * 4;
#pragma unroll
                for (int j = 0; j < 4; ++j) {
                    float bv = bias[n0 + wc * 64 + j * 16 + l16];
#pragma unroll
                    for (int r = 0; r < 4; ++r)
                        rp[(ml + r) * 68 + j * 16 + l16] =
                            f2bf(gelu_exact(acc[i][j][r] + bv));
                }
            }
#pragma unroll
            for (int it = 0; it < 4; ++it) {
                int row = it * 8 + (lane >> 3);            // m local
                int off = (lane & 7) * 8;                  // n chunk
                *(short8*)(Cb + (size_t)(m0 + wr * 64 + 32 * ph + row) * N
                              + n0 + wc * 64 + off) =
                    *(const short8*)(rp + row * 68 + off);
            }
        }
        return;
    }

    // MODE 1: f32 + bias + resid, direct stores (full 64B lines per quad)
    float* Cf = (float*)Cout;
#pragma unroll
    for (int j = 0; j < 4; ++j) {
        int n = n0 + wc * 64 + j * 16 + l16;
        float bv = bias[n];
#pragma unroll
        for (int i = 0; i < 4; ++i) {
            int mbase = m0 + wr * 64 + i * 16 + quad * 4;
#pragma unroll
            for (int r = 0; r < 4; ++r) {
                size_t idx = (size_t)(mbase + r) * N + n;
                Cf[idx] = acc[i][j][r] + bv + resid[idx];
            }
        }
    }
}

// ---------------- MFMA sliding-window attention ----------------
// One block: one (b,h), 64-query tile. Keys [q0-128, q0+64) = 192.
// Qg/Kg: [bh][t][64] bf16; Vtg: [bh][64][2048] bf16 (dim-major). ctx: (B,T,512) bf16.
constexpr int QS = 72;    // Qs/Ks LDS row stride (shorts)
constexpr int VS = 200;   // Vt/Ps LDS row stride (shorts)

__global__ __launch_bounds__(256) void attn_mfma(const short* __restrict__ Qg,
                                                 const short* __restrict__ Kg,
                                                 const short* __restrict__ Vtg,
                                                 short* __restrict__ ctx)
{
    __shared__ short Qs[64 * QS];
    __shared__ short Ks[192 * QS];     // aliased as Ps[64*VS] later
    __shared__ short Vt[64 * VS];
    int tid = threadIdx.x;
    int w = tid >> 6, lane = tid & 63, quad = lane >> 4, l16 = lane & 15;
    int blk = blockIdx.x;
    int q0 = (blk & 31) << 6;
    int bh = blk >> 5;
    int kbase = q0 - 128;

    {
        const short* src = Qg + ((size_t)bh * 2048 + q0) * 64;
        for (int c = tid; c < 512; c += 256) {
            int row = c >> 3, off = (c & 7) * 8;
            *(short8*)(Qs + row * QS + off) = *(const short8*)(src + row * 64 + off);
        }
    }
    {
        const short* base = Kg + (size_t)bh * 2048 * 64;
        for (int c = tid; c < 1536; c += 256) {
            int row = c >> 3, off = (c & 7) * 8;
            int srow = kbase + row; srow = srow < 0 ? 0 : srow;
            *(short8*)(Ks + row * QS + off) = *(const short8*)(base + (size_t)srow * 64 + off);
        }
    }
    {
        const short* base = Vtg + (size_t)bh * 64 * 2048;
        for (int c = tid; c < 1536; c += 256) {
            int row = c / 24, cc = c - row * 24;
            int off = cc * 8;
            int scol = kbase + off; scol = scol < 0 ? 0 : scol;
            *(short8*)(Vt + row * VS + off) = *(const short8*)(base + (size_t)row * 2048 + scol);
        }
    }
    __syncthreads();

    short8 aF0 = *(const short8*)(Qs + (w * 16 + l16) * QS + quad * 8);
    short8 aF1 = *(const short8*)(Qs + (w * 16 + l16) * QS + 32 + quad * 8);
    f32x4 S[12];
    f32x4 zero = {0.f, 0.f, 0.f, 0.f};
#pragma unroll
    for (int t = 0; t < 12; ++t) S[t] = zero;
#pragma unroll
    for (int t = 0; t < 12; ++t) {
        short8 b0 = *(const short8*)(Ks + (t * 16 + l16) * QS + quad * 8);
        short8 b1 = *(const short8*)(Ks + (t * 16 + l16) * QS + 32 + quad * 8);
        S[t] = __builtin_amdgcn_mfma_f32_16x16x32_bf16(aF0, b0, S[t], 0, 0, 0);
        S[t] = __builtin_amdgcn_mfma_f32_16x16x32_bf16(aF1, b1, S[t], 0, 0, 0);
    }

    int i0 = w * 16 + quad * 4;
    float mrow[4] = {-INFINITY, -INFINITY, -INFINITY, -INFINITY};
#pragma unroll
    for (int t = 0; t < 12; ++t) {
        int jl = t * 16 + l16;
        int kg = kbase + jl;
#pragma unroll
        for (int r = 0; r < 4; ++r) {
            int dj = jl - (i0 + r);
            bool ok = (dj >= 1) && (dj <= 128) && (kg >= 0);
            float s = ok ? S[t][r] * 0.125f : -INFINITY;
            S[t][r] = s;
            mrow[r] = fmaxf(mrow[r], s);
        }
    }
#pragma unroll
    for (int off = 8; off >= 1; off >>= 1)
#pragma unroll
        for (int r = 0; r < 4; ++r)
            mrow[r] = fmaxf(mrow[r], __shfl_xor(mrow[r], off, 64));
    float sum[4] = {0.f, 0.f, 0.f, 0.f};
#pragma unroll
    for (int t = 0; t < 12; ++t)
#pragma unroll
        for (int r = 0; r < 4; ++r) {
            float p = __expf(S[t][r] - mrow[r]);
            S[t][r] = p;
            sum[r] += p;
        }
#pragma unroll
    for (int off = 8; off >= 1; off >>= 1)
#pragma unroll
        for (int r = 0; r < 4; ++r)
            sum[r] += __shfl_xor(sum[r], off, 64);
    float inv[4];
#pragma unroll
    for (int r = 0; r < 4; ++r) inv[r] = 1.0f / sum[r];

    __syncthreads();
    short* Ps = Ks;
#pragma unroll
    for (int t = 0; t < 12; ++t)
#pragma unroll
        for (int r = 0; r < 4; ++r)
            Ps[(w * 16 + quad * 4 + r) * VS + t * 16 + l16] = f2bf(S[t][r]);

    f32x4 O[4];
#pragma unroll
    for (int tN = 0; tN < 4; ++tN) O[tN] = zero;
#pragma unroll
    for (int s = 0; s < 6; ++s) {
        short8 aP = *(const short8*)(Ps + (w * 16 + l16) * VS + s * 32 + quad * 8);
#pragma unroll
        for (int tN = 0; tN < 4; ++tN) {
            short8 bV = *(const short8*)(Vt + (tN * 16 + l16) * VS + s * 32 + quad * 8);
            O[tN] = __builtin_amdgcn_mfma_f32_16x16x32_bf16(aP, bV, O[tN], 0, 0, 0);
        }
    }

    int b = bh >> 3, h = bh & 7;
#pragma unroll
    for (int tN = 0; tN < 4; ++tN)
#pragma unroll
        for (int r = 0; r < 4; ++r) {
            int trow = q0 + w * 16 + quad * 4 + r;
            ctx[((size_t)(b * 2048 + trow)) * 512 + h * 64 + tN * 16 + l16] =
                f2bf(O[tN][r] * inv[r]);
        }
}

extern "C" void kernel_launch(void* const* d_in, const int* in_sizes, int n_in,
                              void* d_out, int out_size, void* d_ws, size_t ws_size,
                              hipStream_t stream)
{
    const float* x         = (const float*)d_in[0];
    const float* in_proj_w = (const float*)d_in[1];
    const float* in_proj_b = (const float*)d_in[2];
    const float* out_w     = (const float*)d_in[3];
    const float* out_b     = (const float*)d_in[4];
    const float* ln1_g     = (const float*)d_in[5];
    const float* ln1_b     = (const float*)d_in[6];
    const float* ln2_g     = (const float*)d_in[7];
    const float* ln2_b     = (const float*)d_in[8];
    const float* w1        = (const float*)d_in[9];
    const float* b1        = (const float*)d_in[10];
    const float* w2        = (const float*)d_in[11];
    const float* b2        = (const float*)d_in[12];
    float* out = (float*)d_out;

    char* ws = (char*)d_ws;
    short* attnQ = (short*)ws;
    short* attnK = (short*)(ws + (size_t)8 * 1024 * 1024);
    short* attnV = (short*)(ws + (size_t)16 * 1024 * 1024);
    short* hbuf  = (short*)ws;                                  // overlays attnQKV
    short* regB  = (short*)(ws + (size_t)32 * 1024 * 1024);
    short* wq  = (short*)(ws + (size_t)40 * 1024 * 1024);
    short* wo  = wq + (size_t)QKVD * Dn;
    short* w1b = wo + (size_t)Dn * Dn;
    short* w2b = w1b + (size_t)Fn * Dn;

    // all weight conversions in one launch
    cvt_all<<<3072, 256, 0, stream>>>(in_proj_w, out_w, w1, w2, wq, wo, w1b, w2b);

    // 1) x2 = LN1(x) -> bf16
    ln_kernel<<<Mrows, 64, 0, stream>>>(x, ln1_g, ln1_b, regB);
    // 2) qkv = x2 @ in_proj_w^T + b -> bf16 attention layouts
    gemm_mfma<3, 32><<<(Mrows / 128) * (QKVD / 128), 256, 0, stream>>>(
        regB, wq, in_proj_b, nullptr, nullptr, attnQ, attnK, attnV, Mrows, QKVD, Dn);
    // 3) ctx = attention -> bf16 (B,T,512)
    attn_mfma<<<Bn * Hn * (Tn / 64), 256, 0, stream>>>(attnQ, attnK, attnV, regB);
    // 4) out = x + ctx @ out_w^T + out_b -> f32
    gemm_mfma<1, 64><<<(Mrows / 128) * (Dn / 128), 256, 0, stream>>>(
        regB, wo, out_b, x, out, nullptr, nullptr, nullptr, Mrows, Dn, Dn);
    // 5) x3 = LN2(out) -> bf16
    ln_kernel<<<Mrows, 64, 0, stream>>>(out, ln2_g, ln2_b, regB);
    // 6) h = gelu(x3 @ w1^T + b1) -> bf16 (overlays dead attn buffers)
    gemm_mfma<2, 32><<<(Mrows / 128) * (Fn / 128), 256, 0, stream>>>(
        regB, w1b, b1, nullptr, hbuf, nullptr, nullptr, nullptr, Mrows, Fn, Dn);
    // 7) out = out + h @ w2^T + b2 -> f32
    gemm_mfma<1, 64><<<(Mrows / 128) * (Dn / 128), 256, 0, stream>>>(
        hbuf, w2b, b2, out, out, nullptr, nullptr, nullptr, Mrows, Dn, Fn);
}